// Round 5
// baseline (189.644 us; speedup 1.0000x reference)
//
#include <hip/hip_runtime.h>
#include <cstddef>

#define ALPHA 0.2f
constexpr int B = 2, N = 8192, F = 256, D = 128;
constexpr int M = B * N;
constexpr int NB = 2048;          // value buckets per batch
constexpr int SUB = 256;          // elements per sub-block for stable scatter
constexpr int P = N / SUB;        // 32 sub-blocks per batch
constexpr int GB = 8;             // buckets per k_bsum block
constexpr int NBB = NB / GB;      // 256 bsum blocks per batch
constexpr int GSZ = 64;           // buckets per scan group
constexpr int NGRP = NB / GSZ;    // 32 groups per batch

// ---- fixed monotone bucket map (correct for ANY input via clamping;
// [-10,10] is ~10 sigma for this problem's f2 distribution) ----
#define BMIN (-10.0f)
#define BSCALE ((float)NB / 20.0f)
__device__ inline int bucket_of(float x) {
  int g = (int)((x - BMIN) * BSCALE);
  return g < 0 ? 0 : (g > NB - 1 ? NB - 1 : g);
}

// ---------------- GEMM + fused f1/f2 epilogue ----------------
// 64-row tile, 512 threads (8 waves/CU), 4x4 per-thread tile.
__global__ __launch_bounds__(512) void k_gemm(const float* __restrict__ seq,
                                              const float* __restrict__ Wf,
                                              const float* __restrict__ w1,
                                              const float* __restrict__ b1,
                                              const float* __restrict__ w2,
                                              const float* __restrict__ b2,
                                              float* __restrict__ fts,
                                              float* __restrict__ f1,
                                              float* __restrict__ f2) {
  __shared__ float As[64][36];
  __shared__ float Bs[32][128];
  const int m0 = blockIdx.x * 64;
  const int t = threadIdx.x;
  const int colg = t & 31;        // cols colg*4 .. +3
  const int rowg = t >> 5;        // rows rowg*4 .. +3 (16 groups)
  float acc[4][4];
#pragma unroll
  for (int r = 0; r < 4; ++r)
#pragma unroll
    for (int c = 0; c < 4; ++c) acc[r][c] = 0.f;

  for (int kc = 0; kc < F; kc += 32) {
    {  // A tile 64x32: one float4 per thread
      int row = t >> 3, wi = t & 7;
      const float4 v = *reinterpret_cast<const float4*>(
          &seq[(size_t)(m0 + row) * F + kc + wi * 4]);
      As[row][wi * 4 + 0] = v.x; As[row][wi * 4 + 1] = v.y;
      As[row][wi * 4 + 2] = v.z; As[row][wi * 4 + 3] = v.w;
    }
#pragma unroll
    for (int it = 0; it < 2; ++it) {  // B tile 32x128: two float4 per thread
      int f = t + it * 512;
      int row = f >> 5, c4 = f & 31;
      *reinterpret_cast<float4*>(&Bs[row][c4 * 4]) =
          *reinterpret_cast<const float4*>(&Wf[(size_t)(kc + row) * D + c4 * 4]);
    }
    __syncthreads();
#pragma unroll
    for (int k = 0; k < 32; ++k) {
      float4 b4 = *reinterpret_cast<const float4*>(&Bs[k][colg * 4]);
#pragma unroll
      for (int r = 0; r < 4; ++r) {
        float a = As[rowg * 4 + r][k];
        acc[r][0] += a * b4.x; acc[r][1] += a * b4.y;
        acc[r][2] += a * b4.z; acc[r][3] += a * b4.w;
      }
    }
    __syncthreads();
  }
  // store fts
#pragma unroll
  for (int r = 0; r < 4; ++r) {
    float4 v = {acc[r][0], acc[r][1], acc[r][2], acc[r][3]};
    *reinterpret_cast<float4*>(&fts[(size_t)(m0 + rowg * 4 + r) * D + colg * 4]) = v;
  }
  // fused f1/f2: per-row dot with w1/w2, reduce across the 32 lanes of each row-group
  const float w1v[4] = {w1[colg * 4], w1[colg * 4 + 1], w1[colg * 4 + 2], w1[colg * 4 + 3]};
  const float w2v[4] = {w2[colg * 4], w2[colg * 4 + 1], w2[colg * 4 + 2], w2[colg * 4 + 3]};
  const float b1v = b1[0], b2v = b2[0];
#pragma unroll
  for (int r = 0; r < 4; ++r) {
    float s1 = acc[r][0] * w1v[0] + acc[r][1] * w1v[1] + acc[r][2] * w1v[2] + acc[r][3] * w1v[3];
    float s2 = acc[r][0] * w2v[0] + acc[r][1] * w2v[1] + acc[r][2] * w2v[2] + acc[r][3] * w2v[3];
#pragma unroll
    for (int off = 16; off > 0; off >>= 1) {
      s1 += __shfl_down(s1, off, 32);
      s2 += __shfl_down(s2, off, 32);
    }
    if (colg == 0) {
      const int row = m0 + rowg * 4 + r;
      f1[row] = s1 + b1v;
      f2[row] = s2 + b2v;
    }
  }
}

// ---------------- per-sub-block histogram (deterministic) ----------------
__global__ __launch_bounds__(256) void k_hist(const float* __restrict__ f2,
                                              int* __restrict__ bid,
                                              int* __restrict__ histcnt) {
  __shared__ int hist[NB];
  const int b = blockIdx.x / P, p = blockIdx.x % P;
  const int t = threadIdx.x;
  for (int i = t; i < NB; i += 256) hist[i] = 0;
  const int j = p * SUB + t;
  float x = f2[b * N + j];
  int g = bucket_of(x);
  bid[b * N + j] = g;
  __syncthreads();
  atomicAdd(&hist[g], 1);
  __syncthreads();
  for (int i = t; i < NB; i += 256)
    histcnt[((size_t)(b * P + p)) * NB + i] = hist[i];
}

// ---------------- bucket-count reduce + exclusive scan (shuffle, 2 barriers) ----------------
__global__ __launch_bounds__(1024) void k_bscan(const int* __restrict__ histcnt,
                                                int* __restrict__ bstart) {
  __shared__ int wsum[16];
  const int b = blockIdx.x, t = threadIdx.x;
  const int lane = t & 63, wave = t >> 6;
  int c0 = 0, c1 = 0;
  const int g0 = 2 * t, g1 = 2 * t + 1;
  for (int p = 0; p < P; ++p) {
    const int* h = &histcnt[((size_t)(b * P + p)) * NB];
    c0 += h[g0]; c1 += h[g1];
  }
  const int local = c0 + c1;
  int incl = local;
#pragma unroll
  for (int off = 1; off < 64; off <<= 1) {
    int y = __shfl_up(incl, off);
    if (lane >= off) incl += y;
  }
  if (lane == 63) wsum[wave] = incl;
  __syncthreads();
  if (t < 16) {
    int v = wsum[t];
#pragma unroll
    for (int off = 1; off < 16; off <<= 1) {
      int y = __shfl_up(v, off, 16);
      if (t >= off) v += y;
    }
    wsum[t] = v;
  }
  __syncthreads();
  const int woff = (wave > 0) ? wsum[wave - 1] : 0;
  incl += woff;
  const int excl = incl - local;
  bstart[b * (NB + 1) + g0] = excl;
  bstart[b * (NB + 1) + g1] = excl + c0;
  if (t == 1023) bstart[b * (NB + 1) + NB] = incl;
}

// ---------------- stable deterministic scatter + weight precompute ----------------
__global__ __launch_bounds__(256) void k_scatter(const float* __restrict__ f2,
                                                 const int* __restrict__ bid,
                                                 const int* __restrict__ histcnt,
                                                 const int* __restrict__ bstart,
                                                 float* __restrict__ f2s,
                                                 int* __restrict__ idxs,
                                                 float* __restrict__ wps,
                                                 float* __restrict__ wns) {
  __shared__ int bids[SUB];
  const int b = blockIdx.x / P, p = blockIdx.x % P;
  const int t = threadIdx.x;
  const int j = p * SUB + t;
  const int g = bid[b * N + j];
  bids[t] = g;
  __syncthreads();
  int off = bstart[b * (NB + 1) + g];
  for (int pp = 0; pp < p; ++pp) off += histcnt[((size_t)(b * P + pp)) * NB + g];
  for (int jj = 0; jj < t; ++jj) off += (bids[jj] == g);
  const float x = f2[b * N + j];
  f2s[b * N + off] = x;
  idxs[b * N + off] = j;
  wps[b * N + off] = expf(x);
  wns[b * N + off] = expf(ALPHA * x);
}

// ---------------- per-bucket weighted sums (segmented, deterministic) ----------------
__global__ __launch_bounds__(128) void k_bsum(const float* __restrict__ fts,
                                              const int* __restrict__ idxs,
                                              const float* __restrict__ wps,
                                              const float* __restrict__ wns,
                                              const int* __restrict__ bstart,
                                              float* __restrict__ Wp, float* __restrict__ Wn,
                                              float* __restrict__ Cp, float* __restrict__ Cn) {
  const int b = blockIdx.x / NBB, blk = blockIdx.x % NBB;
  const int d = threadIdx.x;
  const int gbase = blk * GB;
  for (int gg = 0; gg < GB; ++gg) {
    const int g = gbase + gg;
    const int e0 = bstart[b * (NB + 1) + g], e1 = bstart[b * (NB + 1) + g + 1];
    float ap = 0.f, an = 0.f, sp = 0.f, sn = 0.f;
    for (int e = e0; e < e1; ++e) {
      const int j = idxs[b * N + e];
      const float v = fts[((size_t)b * N + j) * D + d];
      const float wp = wps[b * N + e], wn = wns[b * N + e];
      ap += wp * v; an += wn * v; sp += wp; sn += wn;
    }
    Wp[((size_t)b * NB + g) * D + d] = ap;
    Wn[((size_t)b * NB + g) * D + d] = an;
    if (d == 0) { Cp[b * NB + g] = sp; Cn[b * NB + g] = sn; }
  }
}

// ---------------- group sums (64 buckets per group) ----------------
__global__ __launch_bounds__(128) void k_gsumA(const float* __restrict__ Wp, const float* __restrict__ Wn,
                                               const float* __restrict__ Cp, const float* __restrict__ Cn,
                                               float* __restrict__ Gp, float* __restrict__ Gn,
                                               float* __restrict__ SGp, float* __restrict__ SGn) {
  const int b = blockIdx.x / NGRP, grp = blockIdx.x % NGRP;
  const int d = threadIdx.x;
  float sp = 0.f, sn = 0.f, cp = 0.f, cn = 0.f;
  for (int gg = 0; gg < GSZ; ++gg) {
    const int g = grp * GSZ + gg;
    sp += Wp[((size_t)b * NB + g) * D + d];
    sn += Wn[((size_t)b * NB + g) * D + d];
    if (d == 0) { cp += Cp[b * NB + g]; cn += Cn[b * NB + g]; }
  }
  Gp[((size_t)b * NGRP + grp) * D + d] = sp;
  Gn[((size_t)b * NGRP + grp) * D + d] = sn;
  if (d == 0) { SGp[b * NGRP + grp] = cp; SGn[b * NGRP + grp] = cn; }
}

// ---------------- scan the 32 group sums ----------------
__global__ __launch_bounds__(128) void k_gscanB(float* __restrict__ Gp, float* __restrict__ Gn,
                                                float* __restrict__ SGp, float* __restrict__ SGn) {
  const int b = blockIdx.x, d = threadIdx.x;
  float run = 0.f;
  for (int grp = 0; grp < NGRP; ++grp) {
    float t = Gn[((size_t)b * NGRP + grp) * D + d];
    Gn[((size_t)b * NGRP + grp) * D + d] = run; run += t;
  }
  run = 0.f;
  for (int grp = NGRP - 1; grp >= 0; --grp) {
    float t = Gp[((size_t)b * NGRP + grp) * D + d];
    Gp[((size_t)b * NGRP + grp) * D + d] = run; run += t;
  }
  if (d == 0) {
    float r = 0.f;
    for (int grp = 0; grp < NGRP; ++grp) { float t = SGn[b * NGRP + grp]; SGn[b * NGRP + grp] = r; r += t; }
    r = 0.f;
    for (int grp = NGRP - 1; grp >= 0; --grp) { float t = SGp[b * NGRP + grp]; SGp[b * NGRP + grp] = r; r += t; }
  }
}

// ---------------- within-group exclusive scans -> bucket-boundary sums ----------------
__global__ __launch_bounds__(128) void k_gscanC(const float* __restrict__ Wp, const float* __restrict__ Wn,
                                                const float* __restrict__ Cp, const float* __restrict__ Cn,
                                                const float* __restrict__ Gp, const float* __restrict__ Gn,
                                                const float* __restrict__ SGp, const float* __restrict__ SGn,
                                                float* __restrict__ BPos, float* __restrict__ BNeg,
                                                float* __restrict__ CpB, float* __restrict__ CnB) {
  const int b = blockIdx.x / NGRP, grp = blockIdx.x % NGRP;
  const int d = threadIdx.x;
  float runn = Gn[((size_t)b * NGRP + grp) * D + d];
  for (int gg = 0; gg < GSZ; ++gg) {
    const int g = grp * GSZ + gg;
    BNeg[((size_t)b * NB + g) * D + d] = runn;
    runn += Wn[((size_t)b * NB + g) * D + d];
  }
  float runp = Gp[((size_t)b * NGRP + grp) * D + d];
  for (int gg = GSZ - 1; gg >= 0; --gg) {
    const int g = grp * GSZ + gg;
    BPos[((size_t)b * NB + g) * D + d] = runp;
    runp += Wp[((size_t)b * NB + g) * D + d];
  }
  if (d == 0) {
    float r = SGn[b * NGRP + grp];
    for (int gg = 0; gg < GSZ; ++gg) { const int g = grp * GSZ + gg; CnB[b * NB + g] = r; r += Cn[b * NB + g]; }
    r = SGp[b * NGRP + grp];
    for (int gg = GSZ - 1; gg >= 0; --gg) { const int g = grp * GSZ + gg; CpB[b * NB + g] = r; r += Cp[b * NB + g]; }
  }
}

// ---------------- query ----------------
__global__ __launch_bounds__(128) void k_query(const float* __restrict__ f1,
                                               const float* __restrict__ f2s,
                                               const int* __restrict__ idxs,
                                               const float* __restrict__ wps,
                                               const float* __restrict__ wns,
                                               const float* __restrict__ fts,
                                               const int* __restrict__ bstart,
                                               const float* __restrict__ BPos, const float* __restrict__ BNeg,
                                               const float* __restrict__ CpB, const float* __restrict__ CnB,
                                               const float* __restrict__ bias,
                                               float* __restrict__ out) {
  const int row = blockIdx.x;  // b*N + i
  const int b = row / N;
  const int d = threadIdx.x;
  const float f1v = f1[row];
  const float th = -f1v;
  const int g = bucket_of(th);
  const int base = bstart[b * (NB + 1) + g];
  const int end  = bstart[b * (NB + 1) + g + 1];
  float sn = BNeg[((size_t)b * NB + g) * D + d];
  float sp = BPos[((size_t)b * NB + g) * D + d];
  float cn = CnB[b * NB + g];
  float cp = CpB[b * NB + g];
  for (int e = base; e < end; ++e) {
    const float key = f2s[b * N + e];
    const int j = idxs[b * N + e];
    const float v = fts[((size_t)b * N + j) * D + d];
    if (key <= th) { const float w = wns[b * N + e]; sn += w * v; cn += w; }
    else           { const float w = wps[b * N + e]; sp += w * v; cp += w; }
  }
  const float wqp = expf(f1v), wqn = expf(ALPHA * f1v);
  const float denom = wqp * cp + wqn * cn;
  float val = (wqp * sp + wqn * sn) / denom + bias[d];
  out[(size_t)row * D + d] = val >= 0.f ? val : ALPHA * val;
}

extern "C" void kernel_launch(void* const* d_in, const int* in_sizes, int n_in,
                              void* d_out, int out_size, void* d_ws, size_t ws_size,
                              hipStream_t stream) {
  const float* seq  = (const float*)d_in[0];
  const float* Wf   = (const float*)d_in[1];
  const float* w1   = (const float*)d_in[2];
  const float* b1   = (const float*)d_in[3];
  const float* w2   = (const float*)d_in[4];
  const float* b2   = (const float*)d_in[5];
  const float* bias = (const float*)d_in[6];
  float* out = (float*)d_out;

  char* ws = (char*)d_ws;
  size_t off = 0;
  auto alloc = [&](size_t bytes) -> void* {
    void* p = ws + off;
    off = (off + bytes + 255) & ~(size_t)255;
    return p;
  };

  float* fts    = (float*)alloc((size_t)M * D * 4);
  float* f1     = (float*)alloc((size_t)M * 4);
  float* f2     = (float*)alloc((size_t)M * 4);
  float* f2s    = (float*)alloc((size_t)M * 4);
  int*   idxs   = (int*)  alloc((size_t)M * 4);
  float* wps    = (float*)alloc((size_t)M * 4);
  float* wns    = (float*)alloc((size_t)M * 4);
  int*   bid    = (int*)  alloc((size_t)M * 4);
  int*   histcnt= (int*)  alloc((size_t)B * P * NB * 4);
  int*   bstart = (int*)  alloc((size_t)B * (NB + 1) * 4);
  float* Wp     = (float*)alloc((size_t)B * NB * D * 4);
  float* Wn     = (float*)alloc((size_t)B * NB * D * 4);
  float* Cp     = (float*)alloc((size_t)B * NB * 4);
  float* Cn     = (float*)alloc((size_t)B * NB * 4);
  float* Gp     = (float*)alloc((size_t)B * NGRP * D * 4);
  float* Gn     = (float*)alloc((size_t)B * NGRP * D * 4);
  float* SGp    = (float*)alloc((size_t)B * NGRP * 4);
  float* SGn    = (float*)alloc((size_t)B * NGRP * 4);
  float* BPos   = (float*)alloc((size_t)B * NB * D * 4);
  float* BNeg   = (float*)alloc((size_t)B * NB * D * 4);
  float* CpB    = (float*)alloc((size_t)B * NB * 4);
  float* CnB    = (float*)alloc((size_t)B * NB * 4);

  hipLaunchKernelGGL(k_gemm,   dim3(M / 64),   dim3(512),  0, stream, seq, Wf, w1, b1, w2, b2, fts, f1, f2);
  hipLaunchKernelGGL(k_hist,   dim3(B * P),    dim3(256),  0, stream, f2, bid, histcnt);
  hipLaunchKernelGGL(k_bscan,  dim3(B),        dim3(1024), 0, stream, histcnt, bstart);
  hipLaunchKernelGGL(k_scatter,dim3(B * P),    dim3(256),  0, stream, f2, bid, histcnt, bstart, f2s, idxs, wps, wns);
  hipLaunchKernelGGL(k_bsum,   dim3(B * NBB),  dim3(128),  0, stream, fts, idxs, wps, wns, bstart, Wp, Wn, Cp, Cn);
  hipLaunchKernelGGL(k_gsumA,  dim3(B * NGRP), dim3(128),  0, stream, Wp, Wn, Cp, Cn, Gp, Gn, SGp, SGn);
  hipLaunchKernelGGL(k_gscanB, dim3(B),        dim3(128),  0, stream, Gp, Gn, SGp, SGn);
  hipLaunchKernelGGL(k_gscanC, dim3(B * NGRP), dim3(128),  0, stream, Wp, Wn, Cp, Cn, Gp, Gn, SGp, SGn,
                     BPos, BNeg, CpB, CnB);
  hipLaunchKernelGGL(k_query,  dim3(M),        dim3(128),  0, stream, f1, f2s, idxs, wps, wns, fts, bstart,
                     BPos, BNeg, CpB, CnB, bias, out);
}

// Round 6
// 136.972 us; speedup vs baseline: 1.3845x; 1.3845x over previous
//
#include <hip/hip_runtime.h>
#include <cstddef>

#define ALPHA 0.2f
constexpr int B = 2, N = 8192, F = 256, D = 128;
constexpr int M = B * N;
constexpr int NB = 2048;          // value buckets per batch
constexpr int SUB = 256;          // elements per sub-block for stable scatter
constexpr int P = N / SUB;        // 32 sub-blocks per batch
constexpr int GB = 8;             // buckets per k_bsum block
constexpr int NBB = NB / GB;      // 256 bsum blocks per batch
constexpr int GSZ = 64;           // buckets per scan group
constexpr int NGRP = NB / GSZ;    // 32 groups per batch

// ---- fixed monotone bucket map (correct for ANY input via clamping) ----
#define BMIN (-10.0f)
#define BSCALE ((float)NB / 20.0f)
__device__ inline int bucket_of(float x) {
  int g = (int)((x - BMIN) * BSCALE);
  return g < 0 ? 0 : (g > NB - 1 ? NB - 1 : g);
}

// ---------------- GEMM + fused f1/f2 epilogue ----------------
__global__ __launch_bounds__(512) void k_gemm(const float* __restrict__ seq,
                                              const float* __restrict__ Wf,
                                              const float* __restrict__ w1,
                                              const float* __restrict__ b1,
                                              const float* __restrict__ w2,
                                              const float* __restrict__ b2,
                                              float* __restrict__ fts,
                                              float* __restrict__ f1,
                                              float* __restrict__ f2) {
  __shared__ float As[64][36];
  __shared__ float Bs[32][128];
  const int m0 = blockIdx.x * 64;
  const int t = threadIdx.x;
  const int colg = t & 31;        // cols colg*4 .. +3
  const int rowg = t >> 5;        // rows rowg*4 .. +3 (16 groups)
  float acc[4][4];
#pragma unroll
  for (int r = 0; r < 4; ++r)
#pragma unroll
    for (int c = 0; c < 4; ++c) acc[r][c] = 0.f;

  for (int kc = 0; kc < F; kc += 32) {
    {  // A tile 64x32
      int row = t >> 3, wi = t & 7;
      const float4 v = *reinterpret_cast<const float4*>(
          &seq[(size_t)(m0 + row) * F + kc + wi * 4]);
      As[row][wi * 4 + 0] = v.x; As[row][wi * 4 + 1] = v.y;
      As[row][wi * 4 + 2] = v.z; As[row][wi * 4 + 3] = v.w;
    }
#pragma unroll
    for (int it = 0; it < 2; ++it) {  // B tile 32x128
      int f = t + it * 512;
      int row = f >> 5, c4 = f & 31;
      *reinterpret_cast<float4*>(&Bs[row][c4 * 4]) =
          *reinterpret_cast<const float4*>(&Wf[(size_t)(kc + row) * D + c4 * 4]);
    }
    __syncthreads();
#pragma unroll
    for (int k = 0; k < 32; ++k) {
      float4 b4 = *reinterpret_cast<const float4*>(&Bs[k][colg * 4]);
#pragma unroll
      for (int r = 0; r < 4; ++r) {
        float a = As[rowg * 4 + r][k];
        acc[r][0] += a * b4.x; acc[r][1] += a * b4.y;
        acc[r][2] += a * b4.z; acc[r][3] += a * b4.w;
      }
    }
    __syncthreads();
  }
#pragma unroll
  for (int r = 0; r < 4; ++r) {
    float4 v = {acc[r][0], acc[r][1], acc[r][2], acc[r][3]};
    *reinterpret_cast<float4*>(&fts[(size_t)(m0 + rowg * 4 + r) * D + colg * 4]) = v;
  }
  const float w1v[4] = {w1[colg * 4], w1[colg * 4 + 1], w1[colg * 4 + 2], w1[colg * 4 + 3]};
  const float w2v[4] = {w2[colg * 4], w2[colg * 4 + 1], w2[colg * 4 + 2], w2[colg * 4 + 3]};
  const float b1v = b1[0], b2v = b2[0];
#pragma unroll
  for (int r = 0; r < 4; ++r) {
    float s1 = acc[r][0] * w1v[0] + acc[r][1] * w1v[1] + acc[r][2] * w1v[2] + acc[r][3] * w1v[3];
    float s2 = acc[r][0] * w2v[0] + acc[r][1] * w2v[1] + acc[r][2] * w2v[2] + acc[r][3] * w2v[3];
#pragma unroll
    for (int off = 16; off > 0; off >>= 1) {
      s1 += __shfl_down(s1, off, 32);
      s2 += __shfl_down(s2, off, 32);
    }
    if (colg == 0) {
      const int row = m0 + rowg * 4 + r;
      f1[row] = s1 + b1v;
      f2[row] = s2 + b2v;
    }
  }
}

// ---------------- per-sub-block histogram (deterministic) ----------------
__global__ __launch_bounds__(256) void k_hist(const float* __restrict__ f2,
                                              int* __restrict__ bid,
                                              int* __restrict__ histcnt) {
  __shared__ int hist[NB];
  const int b = blockIdx.x / P, p = blockIdx.x % P;
  const int t = threadIdx.x;
  for (int i = t; i < NB; i += 256) hist[i] = 0;
  const int j = p * SUB + t;
  float x = f2[b * N + j];
  int g = bucket_of(x);
  bid[b * N + j] = g;
  __syncthreads();
  atomicAdd(&hist[g], 1);
  __syncthreads();
  for (int i = t; i < NB; i += 256)
    histcnt[((size_t)(b * P + p)) * NB + i] = hist[i];
}

// ---------------- bucket-count reduce + exclusive scan (shuffle) ----------------
__global__ __launch_bounds__(1024) void k_bscan(const int* __restrict__ histcnt,
                                                int* __restrict__ bstart) {
  __shared__ int wsum[16];
  const int b = blockIdx.x, t = threadIdx.x;
  const int lane = t & 63, wave = t >> 6;
  int c0 = 0, c1 = 0;
  const int g0 = 2 * t, g1 = 2 * t + 1;
  for (int p = 0; p < P; ++p) {
    const int* h = &histcnt[((size_t)(b * P + p)) * NB];
    c0 += h[g0]; c1 += h[g1];
  }
  const int local = c0 + c1;
  int incl = local;
#pragma unroll
  for (int off = 1; off < 64; off <<= 1) {
    int y = __shfl_up(incl, off);
    if (lane >= off) incl += y;
  }
  if (lane == 63) wsum[wave] = incl;
  __syncthreads();
  if (t < 16) {
    int v = wsum[t];
#pragma unroll
    for (int off = 1; off < 16; off <<= 1) {
      int y = __shfl_up(v, off, 16);
      if (t >= off) v += y;
    }
    wsum[t] = v;
  }
  __syncthreads();
  const int woff = (wave > 0) ? wsum[wave - 1] : 0;
  incl += woff;
  const int excl = incl - local;
  bstart[b * (NB + 1) + g0] = excl;
  bstart[b * (NB + 1) + g1] = excl + c0;
  if (t == 1023) bstart[b * (NB + 1) + NB] = incl;
}

// ---------------- stable deterministic scatter + weight precompute ----------------
__global__ __launch_bounds__(256) void k_scatter(const float* __restrict__ f2,
                                                 const int* __restrict__ bid,
                                                 const int* __restrict__ histcnt,
                                                 const int* __restrict__ bstart,
                                                 float* __restrict__ f2s,
                                                 int* __restrict__ idxs,
                                                 float* __restrict__ wps,
                                                 float* __restrict__ wns) {
  __shared__ int bids[SUB];
  const int b = blockIdx.x / P, p = blockIdx.x % P;
  const int t = threadIdx.x;
  const int j = p * SUB + t;
  const int g = bid[b * N + j];
  bids[t] = g;
  __syncthreads();
  int off = bstart[b * (NB + 1) + g];
  for (int pp = 0; pp < p; ++pp) off += histcnt[((size_t)(b * P + pp)) * NB + g];
  for (int jj = 0; jj < t; ++jj) off += (bids[jj] == g);
  const float x = f2[b * N + j];
  f2s[b * N + off] = x;
  idxs[b * N + off] = j;
  wps[b * N + off] = expf(x);
  wns[b * N + off] = expf(ALPHA * x);
}

// ---------------- permute fts into scattered order (massive-TLP gather) ----------------
__global__ __launch_bounds__(256) void k_perm(const float* __restrict__ fts,
                                              const int* __restrict__ idxs,
                                              float* __restrict__ fts_s) {
  const int tid = blockIdx.x * 256 + threadIdx.x;    // one float4 each
  const int eg = tid >> 5;                           // global scattered row (b*N+e)
  const int q = tid & 31;                            // float4 index in row
  const int b = eg / N;
  const int j = idxs[eg];                            // original row within batch
  *reinterpret_cast<float4*>(&fts_s[(size_t)eg * D + q * 4]) =
      *reinterpret_cast<const float4*>(&fts[((size_t)b * N + j) * D + q * 4]);
}

// ---------------- per-bucket weighted sums (streaming, unroll 4) ----------------
__global__ __launch_bounds__(128) void k_bsum(const float* __restrict__ fts_s,
                                              const float* __restrict__ wps,
                                              const float* __restrict__ wns,
                                              const int* __restrict__ bstart,
                                              float* __restrict__ Wp, float* __restrict__ Wn,
                                              float* __restrict__ Cp, float* __restrict__ Cn) {
  const int b = blockIdx.x / NBB, blk = blockIdx.x % NBB;
  const int d = threadIdx.x;
  const int gbase = blk * GB;
  const size_t bN = (size_t)b * N;
  for (int gg = 0; gg < GB; ++gg) {
    const int g = gbase + gg;
    const int e0 = bstart[b * (NB + 1) + g], e1 = bstart[b * (NB + 1) + g + 1];
    float ap = 0.f, an = 0.f, sp = 0.f, sn = 0.f;
    int e = e0;
    for (; e + 4 <= e1; e += 4) {
      const float* vp = &fts_s[(bN + e) * D + d];
      const float v0 = vp[0], v1 = vp[D], v2 = vp[2 * D], v3 = vp[3 * D];
      const float p0 = wps[bN + e], p1 = wps[bN + e + 1], p2 = wps[bN + e + 2], p3 = wps[bN + e + 3];
      const float n0 = wns[bN + e], n1 = wns[bN + e + 1], n2 = wns[bN + e + 2], n3 = wns[bN + e + 3];
      ap += p0 * v0 + p1 * v1 + p2 * v2 + p3 * v3;
      an += n0 * v0 + n1 * v1 + n2 * v2 + n3 * v3;
      sp += p0 + p1 + p2 + p3;
      sn += n0 + n1 + n2 + n3;
    }
    for (; e < e1; ++e) {
      const float v = fts_s[(bN + e) * D + d];
      const float wp = wps[bN + e], wn = wns[bN + e];
      ap += wp * v; an += wn * v; sp += wp; sn += wn;
    }
    Wp[((size_t)b * NB + g) * D + d] = ap;
    Wn[((size_t)b * NB + g) * D + d] = an;
    if (d == 0) { Cp[b * NB + g] = sp; Cn[b * NB + g] = sn; }
  }
}

// ---------------- group sums (64 buckets per group) ----------------
__global__ __launch_bounds__(128) void k_gsumA(const float* __restrict__ Wp, const float* __restrict__ Wn,
                                               const float* __restrict__ Cp, const float* __restrict__ Cn,
                                               float* __restrict__ Gp, float* __restrict__ Gn,
                                               float* __restrict__ SGp, float* __restrict__ SGn) {
  const int b = blockIdx.x / NGRP, grp = blockIdx.x % NGRP;
  const int d = threadIdx.x;
  float sp = 0.f, sn = 0.f, cp = 0.f, cn = 0.f;
  for (int gg = 0; gg < GSZ; ++gg) {
    const int g = grp * GSZ + gg;
    sp += Wp[((size_t)b * NB + g) * D + d];
    sn += Wn[((size_t)b * NB + g) * D + d];
    if (d == 0) { cp += Cp[b * NB + g]; cn += Cn[b * NB + g]; }
  }
  Gp[((size_t)b * NGRP + grp) * D + d] = sp;
  Gn[((size_t)b * NGRP + grp) * D + d] = sn;
  if (d == 0) { SGp[b * NGRP + grp] = cp; SGn[b * NGRP + grp] = cn; }
}

// ---------------- scan the 32 group sums ----------------
__global__ __launch_bounds__(128) void k_gscanB(float* __restrict__ Gp, float* __restrict__ Gn,
                                                float* __restrict__ SGp, float* __restrict__ SGn) {
  const int b = blockIdx.x, d = threadIdx.x;
  float run = 0.f;
  for (int grp = 0; grp < NGRP; ++grp) {
    float t = Gn[((size_t)b * NGRP + grp) * D + d];
    Gn[((size_t)b * NGRP + grp) * D + d] = run; run += t;
  }
  run = 0.f;
  for (int grp = NGRP - 1; grp >= 0; --grp) {
    float t = Gp[((size_t)b * NGRP + grp) * D + d];
    Gp[((size_t)b * NGRP + grp) * D + d] = run; run += t;
  }
  if (d == 0) {
    float r = 0.f;
    for (int grp = 0; grp < NGRP; ++grp) { float t = SGn[b * NGRP + grp]; SGn[b * NGRP + grp] = r; r += t; }
    r = 0.f;
    for (int grp = NGRP - 1; grp >= 0; --grp) { float t = SGp[b * NGRP + grp]; SGp[b * NGRP + grp] = r; r += t; }
  }
}

// ---------------- within-group exclusive scans -> bucket-boundary sums ----------------
__global__ __launch_bounds__(128) void k_gscanC(const float* __restrict__ Wp, const float* __restrict__ Wn,
                                                const float* __restrict__ Cp, const float* __restrict__ Cn,
                                                const float* __restrict__ Gp, const float* __restrict__ Gn,
                                                const float* __restrict__ SGp, const float* __restrict__ SGn,
                                                float* __restrict__ BPos, float* __restrict__ BNeg,
                                                float* __restrict__ CpB, float* __restrict__ CnB) {
  const int b = blockIdx.x / NGRP, grp = blockIdx.x % NGRP;
  const int d = threadIdx.x;
  float runn = Gn[((size_t)b * NGRP + grp) * D + d];
  for (int gg = 0; gg < GSZ; ++gg) {
    const int g = grp * GSZ + gg;
    BNeg[((size_t)b * NB + g) * D + d] = runn;
    runn += Wn[((size_t)b * NB + g) * D + d];
  }
  float runp = Gp[((size_t)b * NGRP + grp) * D + d];
  for (int gg = GSZ - 1; gg >= 0; --gg) {
    const int g = grp * GSZ + gg;
    BPos[((size_t)b * NB + g) * D + d] = runp;
    runp += Wp[((size_t)b * NB + g) * D + d];
  }
  if (d == 0) {
    float r = SGn[b * NGRP + grp];
    for (int gg = 0; gg < GSZ; ++gg) { const int g = grp * GSZ + gg; CnB[b * NB + g] = r; r += Cn[b * NB + g]; }
    r = SGp[b * NGRP + grp];
    for (int gg = GSZ - 1; gg >= 0; --gg) { const int g = grp * GSZ + gg; CpB[b * NB + g] = r; r += Cp[b * NB + g]; }
  }
}

// ---------------- query ----------------
__global__ __launch_bounds__(128) void k_query(const float* __restrict__ f1,
                                               const float* __restrict__ f2s,
                                               const float* __restrict__ wps,
                                               const float* __restrict__ wns,
                                               const float* __restrict__ fts_s,
                                               const int* __restrict__ bstart,
                                               const float* __restrict__ BPos, const float* __restrict__ BNeg,
                                               const float* __restrict__ CpB, const float* __restrict__ CnB,
                                               const float* __restrict__ bias,
                                               float* __restrict__ out) {
  const int row = blockIdx.x;  // b*N + i
  const int b = row / N;
  const int d = threadIdx.x;
  const size_t bN = (size_t)b * N;
  const float f1v = f1[row];
  const float th = -f1v;
  const int g = bucket_of(th);
  const int base = bstart[b * (NB + 1) + g];
  const int end  = bstart[b * (NB + 1) + g + 1];
  float sn = BNeg[((size_t)b * NB + g) * D + d];
  float sp = BPos[((size_t)b * NB + g) * D + d];
  float cn = CnB[b * NB + g];
  float cp = CpB[b * NB + g];
  for (int e = base; e < end; ++e) {
    const float key = f2s[bN + e];
    const float v = fts_s[(bN + e) * D + d];
    if (key <= th) { const float w = wns[bN + e]; sn += w * v; cn += w; }
    else           { const float w = wps[bN + e]; sp += w * v; cp += w; }
  }
  const float wqp = expf(f1v), wqn = expf(ALPHA * f1v);
  const float denom = wqp * cp + wqn * cn;
  float val = (wqp * sp + wqn * sn) / denom + bias[d];
  out[(size_t)row * D + d] = val >= 0.f ? val : ALPHA * val;
}

extern "C" void kernel_launch(void* const* d_in, const int* in_sizes, int n_in,
                              void* d_out, int out_size, void* d_ws, size_t ws_size,
                              hipStream_t stream) {
  const float* seq  = (const float*)d_in[0];
  const float* Wf   = (const float*)d_in[1];
  const float* w1   = (const float*)d_in[2];
  const float* b1   = (const float*)d_in[3];
  const float* w2   = (const float*)d_in[4];
  const float* b2   = (const float*)d_in[5];
  const float* bias = (const float*)d_in[6];
  float* out = (float*)d_out;

  char* ws = (char*)d_ws;
  size_t off = 0;
  auto alloc = [&](size_t bytes) -> void* {
    void* p = ws + off;
    off = (off + bytes + 255) & ~(size_t)255;
    return p;
  };

  float* fts    = (float*)alloc((size_t)M * D * 4);
  float* fts_s  = (float*)alloc((size_t)M * D * 4);
  float* f1     = (float*)alloc((size_t)M * 4);
  float* f2     = (float*)alloc((size_t)M * 4);
  float* f2s    = (float*)alloc((size_t)M * 4);
  int*   idxs   = (int*)  alloc((size_t)M * 4);
  float* wps    = (float*)alloc((size_t)M * 4);
  float* wns    = (float*)alloc((size_t)M * 4);
  int*   bid    = (int*)  alloc((size_t)M * 4);
  int*   histcnt= (int*)  alloc((size_t)B * P * NB * 4);
  int*   bstart = (int*)  alloc((size_t)B * (NB + 1) * 4);
  float* Wp     = (float*)alloc((size_t)B * NB * D * 4);
  float* Wn     = (float*)alloc((size_t)B * NB * D * 4);
  float* Cp     = (float*)alloc((size_t)B * NB * 4);
  float* Cn     = (float*)alloc((size_t)B * NB * 4);
  float* Gp     = (float*)alloc((size_t)B * NGRP * D * 4);
  float* Gn     = (float*)alloc((size_t)B * NGRP * D * 4);
  float* SGp    = (float*)alloc((size_t)B * NGRP * 4);
  float* SGn    = (float*)alloc((size_t)B * NGRP * 4);
  float* BPos   = (float*)alloc((size_t)B * NB * D * 4);
  float* BNeg   = (float*)alloc((size_t)B * NB * D * 4);
  float* CpB    = (float*)alloc((size_t)B * NB * 4);
  float* CnB    = (float*)alloc((size_t)B * NB * 4);

  hipLaunchKernelGGL(k_gemm,   dim3(M / 64),     dim3(512),  0, stream, seq, Wf, w1, b1, w2, b2, fts, f1, f2);
  hipLaunchKernelGGL(k_hist,   dim3(B * P),      dim3(256),  0, stream, f2, bid, histcnt);
  hipLaunchKernelGGL(k_bscan,  dim3(B),          dim3(1024), 0, stream, histcnt, bstart);
  hipLaunchKernelGGL(k_scatter,dim3(B * P),      dim3(256),  0, stream, f2, bid, histcnt, bstart, f2s, idxs, wps, wns);
  hipLaunchKernelGGL(k_perm,   dim3(M * D / 4 / 256), dim3(256), 0, stream, fts, idxs, fts_s);
  hipLaunchKernelGGL(k_bsum,   dim3(B * NBB),    dim3(128),  0, stream, fts_s, wps, wns, bstart, Wp, Wn, Cp, Cn);
  hipLaunchKernelGGL(k_gsumA,  dim3(B * NGRP),   dim3(128),  0, stream, Wp, Wn, Cp, Cn, Gp, Gn, SGp, SGn);
  hipLaunchKernelGGL(k_gscanB, dim3(B),          dim3(128),  0, stream, Gp, Gn, SGp, SGn);
  hipLaunchKernelGGL(k_gscanC, dim3(B * NGRP),   dim3(128),  0, stream, Wp, Wn, Cp, Cn, Gp, Gn, SGp, SGn,
                     BPos, BNeg, CpB, CnB);
  hipLaunchKernelGGL(k_query,  dim3(M),          dim3(128),  0, stream, f1, f2s, wps, wns, fts_s, bstart,
                     BPos, BNeg, CpB, CnB, bias, out);
}

// Round 7
// 116.192 us; speedup vs baseline: 1.6322x; 1.1788x over previous
//
#include <hip/hip_runtime.h>
#include <cstddef>

#define ALPHA 0.2f
constexpr int B = 2, N = 8192, F = 256, D = 128;
constexpr int M = B * N;
constexpr int NB = 2048;          // value buckets per batch
constexpr int SUB = 256;          // elements per sub-block for stable scatter
constexpr int P = N / SUB;        // 32 sub-blocks per batch
constexpr int GB = 8;             // buckets per k_bsum block
constexpr int NBB = NB / GB;      // 256 bsum blocks per batch
constexpr int GSZ = 64;           // buckets per scan group
constexpr int NGRP = NB / GSZ;    // 32 groups per batch
constexpr int QROWS = 8;          // rows per k_query block

// ---- fixed monotone bucket map (correct for ANY input via clamping) ----
#define BMIN (-10.0f)
#define BSCALE ((float)NB / 20.0f)
__device__ inline int bucket_of(float x) {
  int g = (int)((x - BMIN) * BSCALE);
  return g < 0 ? 0 : (g > NB - 1 ? NB - 1 : g);
}

// ---------------- GEMM + fused f1/f2 epilogue ----------------
__global__ __launch_bounds__(512) void k_gemm(const float* __restrict__ seq,
                                              const float* __restrict__ Wf,
                                              const float* __restrict__ w1,
                                              const float* __restrict__ b1,
                                              const float* __restrict__ w2,
                                              const float* __restrict__ b2,
                                              float* __restrict__ fts,
                                              float* __restrict__ f1,
                                              float* __restrict__ f2) {
  __shared__ float As[64][36];
  __shared__ float Bs[32][128];
  const int m0 = blockIdx.x * 64;
  const int t = threadIdx.x;
  const int colg = t & 31;        // cols colg*4 .. +3
  const int rowg = t >> 5;        // rows rowg*4 .. +3 (16 groups)
  float acc[4][4];
#pragma unroll
  for (int r = 0; r < 4; ++r)
#pragma unroll
    for (int c = 0; c < 4; ++c) acc[r][c] = 0.f;

  for (int kc = 0; kc < F; kc += 32) {
    {  // A tile 64x32
      int row = t >> 3, wi = t & 7;
      const float4 v = *reinterpret_cast<const float4*>(
          &seq[(size_t)(m0 + row) * F + kc + wi * 4]);
      As[row][wi * 4 + 0] = v.x; As[row][wi * 4 + 1] = v.y;
      As[row][wi * 4 + 2] = v.z; As[row][wi * 4 + 3] = v.w;
    }
#pragma unroll
    for (int it = 0; it < 2; ++it) {  // B tile 32x128
      int f = t + it * 512;
      int row = f >> 5, c4 = f & 31;
      *reinterpret_cast<float4*>(&Bs[row][c4 * 4]) =
          *reinterpret_cast<const float4*>(&Wf[(size_t)(kc + row) * D + c4 * 4]);
    }
    __syncthreads();
#pragma unroll
    for (int k = 0; k < 32; ++k) {
      float4 b4 = *reinterpret_cast<const float4*>(&Bs[k][colg * 4]);
#pragma unroll
      for (int r = 0; r < 4; ++r) {
        float a = As[rowg * 4 + r][k];
        acc[r][0] += a * b4.x; acc[r][1] += a * b4.y;
        acc[r][2] += a * b4.z; acc[r][3] += a * b4.w;
      }
    }
    __syncthreads();
  }
#pragma unroll
  for (int r = 0; r < 4; ++r) {
    float4 v = {acc[r][0], acc[r][1], acc[r][2], acc[r][3]};
    *reinterpret_cast<float4*>(&fts[(size_t)(m0 + rowg * 4 + r) * D + colg * 4]) = v;
  }
  const float w1v[4] = {w1[colg * 4], w1[colg * 4 + 1], w1[colg * 4 + 2], w1[colg * 4 + 3]};
  const float w2v[4] = {w2[colg * 4], w2[colg * 4 + 1], w2[colg * 4 + 2], w2[colg * 4 + 3]};
  const float b1v = b1[0], b2v = b2[0];
#pragma unroll
  for (int r = 0; r < 4; ++r) {
    float s1 = acc[r][0] * w1v[0] + acc[r][1] * w1v[1] + acc[r][2] * w1v[2] + acc[r][3] * w1v[3];
    float s2 = acc[r][0] * w2v[0] + acc[r][1] * w2v[1] + acc[r][2] * w2v[2] + acc[r][3] * w2v[3];
#pragma unroll
    for (int off = 16; off > 0; off >>= 1) {
      s1 += __shfl_down(s1, off, 32);
      s2 += __shfl_down(s2, off, 32);
    }
    if (colg == 0) {
      const int row = m0 + rowg * 4 + r;
      f1[row] = s1 + b1v;
      f2[row] = s2 + b2v;
    }
  }
}

// ---------------- per-sub-block histogram (deterministic) ----------------
__global__ __launch_bounds__(256) void k_hist(const float* __restrict__ f2,
                                              int* __restrict__ bid,
                                              int* __restrict__ histcnt) {
  __shared__ int hist[NB];
  const int b = blockIdx.x / P, p = blockIdx.x % P;
  const int t = threadIdx.x;
  for (int i = t; i < NB; i += 256) hist[i] = 0;
  const int j = p * SUB + t;
  float x = f2[b * N + j];
  int g = bucket_of(x);
  bid[b * N + j] = g;
  __syncthreads();
  atomicAdd(&hist[g], 1);
  __syncthreads();
  for (int i = t; i < NB; i += 256)
    histcnt[((size_t)(b * P + p)) * NB + i] = hist[i];
}

// ---------------- bucket-count reduce + exclusive scan (shuffle) ----------------
__global__ __launch_bounds__(1024) void k_bscan(const int* __restrict__ histcnt,
                                                int* __restrict__ bstart) {
  __shared__ int wsum[16];
  const int b = blockIdx.x, t = threadIdx.x;
  const int lane = t & 63, wave = t >> 6;
  int c0 = 0, c1 = 0;
  const int g0 = 2 * t, g1 = 2 * t + 1;
  for (int p = 0; p < P; ++p) {
    const int* h = &histcnt[((size_t)(b * P + p)) * NB];
    c0 += h[g0]; c1 += h[g1];
  }
  const int local = c0 + c1;
  int incl = local;
#pragma unroll
  for (int off = 1; off < 64; off <<= 1) {
    int y = __shfl_up(incl, off);
    if (lane >= off) incl += y;
  }
  if (lane == 63) wsum[wave] = incl;
  __syncthreads();
  if (t < 16) {
    int v = wsum[t];
#pragma unroll
    for (int off = 1; off < 16; off <<= 1) {
      int y = __shfl_up(v, off, 16);
      if (t >= off) v += y;
    }
    wsum[t] = v;
  }
  __syncthreads();
  const int woff = (wave > 0) ? wsum[wave - 1] : 0;
  incl += woff;
  const int excl = incl - local;
  bstart[b * (NB + 1) + g0] = excl;
  bstart[b * (NB + 1) + g1] = excl + c0;
  if (t == 1023) bstart[b * (NB + 1) + NB] = incl;
}

// ---------------- stable deterministic scatter + weight precompute ----------------
__global__ __launch_bounds__(256) void k_scatter(const float* __restrict__ f2,
                                                 const int* __restrict__ bid,
                                                 const int* __restrict__ histcnt,
                                                 const int* __restrict__ bstart,
                                                 float* __restrict__ f2s,
                                                 int* __restrict__ idxs,
                                                 float* __restrict__ wps,
                                                 float* __restrict__ wns) {
  __shared__ int bids[SUB];
  const int b = blockIdx.x / P, p = blockIdx.x % P;
  const int t = threadIdx.x;
  const int j = p * SUB + t;
  const int g = bid[b * N + j];
  bids[t] = g;
  __syncthreads();
  int off = bstart[b * (NB + 1) + g];
  for (int pp = 0; pp < p; ++pp) off += histcnt[((size_t)(b * P + pp)) * NB + g];
  for (int jj = 0; jj < t; ++jj) off += (bids[jj] == g);
  const float x = f2[b * N + j];
  f2s[b * N + off] = x;
  idxs[b * N + off] = j;
  wps[b * N + off] = expf(x);
  wns[b * N + off] = expf(ALPHA * x);
}

// ---------------- permute fts into scattered order (massive-TLP gather) ----------------
__global__ __launch_bounds__(256) void k_perm(const float* __restrict__ fts,
                                              const int* __restrict__ idxs,
                                              float* __restrict__ fts_s) {
  const int tid = blockIdx.x * 256 + threadIdx.x;    // one float4 each
  const int eg = tid >> 5;                           // global scattered row (b*N+e)
  const int q = tid & 31;                            // float4 index in row
  const int b = eg / N;
  const int j = idxs[eg];                            // original row within batch
  *reinterpret_cast<float4*>(&fts_s[(size_t)eg * D + q * 4]) =
      *reinterpret_cast<const float4*>(&fts[((size_t)b * N + j) * D + q * 4]);
}

// ---------------- per-bucket weighted sums (streaming, unroll 4) ----------------
__global__ __launch_bounds__(128) void k_bsum(const float* __restrict__ fts_s,
                                              const float* __restrict__ wps,
                                              const float* __restrict__ wns,
                                              const int* __restrict__ bstart,
                                              float* __restrict__ Wp, float* __restrict__ Wn,
                                              float* __restrict__ Cp, float* __restrict__ Cn) {
  const int b = blockIdx.x / NBB, blk = blockIdx.x % NBB;
  const int d = threadIdx.x;
  const int gbase = blk * GB;
  const size_t bN = (size_t)b * N;
  for (int gg = 0; gg < GB; ++gg) {
    const int g = gbase + gg;
    const int e0 = bstart[b * (NB + 1) + g], e1 = bstart[b * (NB + 1) + g + 1];
    float ap = 0.f, an = 0.f, sp = 0.f, sn = 0.f;
    int e = e0;
    for (; e + 4 <= e1; e += 4) {
      const float* vp = &fts_s[(bN + e) * D + d];
      const float v0 = vp[0], v1 = vp[D], v2 = vp[2 * D], v3 = vp[3 * D];
      const float p0 = wps[bN + e], p1 = wps[bN + e + 1], p2 = wps[bN + e + 2], p3 = wps[bN + e + 3];
      const float n0 = wns[bN + e], n1 = wns[bN + e + 1], n2 = wns[bN + e + 2], n3 = wns[bN + e + 3];
      ap += p0 * v0 + p1 * v1 + p2 * v2 + p3 * v3;
      an += n0 * v0 + n1 * v1 + n2 * v2 + n3 * v3;
      sp += p0 + p1 + p2 + p3;
      sn += n0 + n1 + n2 + n3;
    }
    for (; e < e1; ++e) {
      const float v = fts_s[(bN + e) * D + d];
      const float wp = wps[bN + e], wn = wns[bN + e];
      ap += wp * v; an += wn * v; sp += wp; sn += wn;
    }
    Wp[((size_t)b * NB + g) * D + d] = ap;
    Wn[((size_t)b * NB + g) * D + d] = an;
    if (d == 0) { Cp[b * NB + g] = sp; Cn[b * NB + g] = sn; }
  }
}

// ---------------- group sums (64 buckets per group) ----------------
__global__ __launch_bounds__(128) void k_gsumA(const float* __restrict__ Wp, const float* __restrict__ Wn,
                                               const float* __restrict__ Cp, const float* __restrict__ Cn,
                                               float* __restrict__ Gp, float* __restrict__ Gn,
                                               float* __restrict__ SGp, float* __restrict__ SGn) {
  const int b = blockIdx.x / NGRP, grp = blockIdx.x % NGRP;
  const int d = threadIdx.x;
  float sp = 0.f, sn = 0.f, cp = 0.f, cn = 0.f;
  for (int gg = 0; gg < GSZ; ++gg) {
    const int g = grp * GSZ + gg;
    sp += Wp[((size_t)b * NB + g) * D + d];
    sn += Wn[((size_t)b * NB + g) * D + d];
    if (d == 0) { cp += Cp[b * NB + g]; cn += Cn[b * NB + g]; }
  }
  Gp[((size_t)b * NGRP + grp) * D + d] = sp;
  Gn[((size_t)b * NGRP + grp) * D + d] = sn;
  if (d == 0) { SGp[b * NGRP + grp] = cp; SGn[b * NGRP + grp] = cn; }
}

// ---------------- scan the 32 group sums ----------------
__global__ __launch_bounds__(128) void k_gscanB(float* __restrict__ Gp, float* __restrict__ Gn,
                                                float* __restrict__ SGp, float* __restrict__ SGn) {
  const int b = blockIdx.x, d = threadIdx.x;
  float run = 0.f;
  for (int grp = 0; grp < NGRP; ++grp) {
    float t = Gn[((size_t)b * NGRP + grp) * D + d];
    Gn[((size_t)b * NGRP + grp) * D + d] = run; run += t;
  }
  run = 0.f;
  for (int grp = NGRP - 1; grp >= 0; --grp) {
    float t = Gp[((size_t)b * NGRP + grp) * D + d];
    Gp[((size_t)b * NGRP + grp) * D + d] = run; run += t;
  }
  if (d == 0) {
    float r = 0.f;
    for (int grp = 0; grp < NGRP; ++grp) { float t = SGn[b * NGRP + grp]; SGn[b * NGRP + grp] = r; r += t; }
    r = 0.f;
    for (int grp = NGRP - 1; grp >= 0; --grp) { float t = SGp[b * NGRP + grp]; SGp[b * NGRP + grp] = r; r += t; }
  }
}

// ---------------- within-group exclusive scans -> bucket-boundary sums ----------------
__global__ __launch_bounds__(128) void k_gscanC(const float* __restrict__ Wp, const float* __restrict__ Wn,
                                                const float* __restrict__ Cp, const float* __restrict__ Cn,
                                                const float* __restrict__ Gp, const float* __restrict__ Gn,
                                                const float* __restrict__ SGp, const float* __restrict__ SGn,
                                                float* __restrict__ BPos, float* __restrict__ BNeg,
                                                float* __restrict__ CpB, float* __restrict__ CnB) {
  const int b = blockIdx.x / NGRP, grp = blockIdx.x % NGRP;
  const int d = threadIdx.x;
  float runn = Gn[((size_t)b * NGRP + grp) * D + d];
  for (int gg = 0; gg < GSZ; ++gg) {
    const int g = grp * GSZ + gg;
    BNeg[((size_t)b * NB + g) * D + d] = runn;
    runn += Wn[((size_t)b * NB + g) * D + d];
  }
  float runp = Gp[((size_t)b * NGRP + grp) * D + d];
  for (int gg = GSZ - 1; gg >= 0; --gg) {
    const int g = grp * GSZ + gg;
    BPos[((size_t)b * NB + g) * D + d] = runp;
    runp += Wp[((size_t)b * NB + g) * D + d];
  }
  if (d == 0) {
    float r = SGn[b * NGRP + grp];
    for (int gg = 0; gg < GSZ; ++gg) { const int g = grp * GSZ + gg; CnB[b * NB + g] = r; r += Cn[b * NB + g]; }
    r = SGp[b * NGRP + grp];
    for (int gg = GSZ - 1; gg >= 0; --gg) { const int g = grp * GSZ + gg; CpB[b * NB + g] = r; r += Cp[b * NB + g]; }
  }
}

// ---------------- query: 32 lanes x float4 per row, branchless boundary loop ----------------
__global__ __launch_bounds__(256) void k_query(const float* __restrict__ f1,
                                               const float* __restrict__ f2s,
                                               const float* __restrict__ wps,
                                               const float* __restrict__ wns,
                                               const float* __restrict__ fts_s,
                                               const int* __restrict__ bstart,
                                               const float* __restrict__ BPos, const float* __restrict__ BNeg,
                                               const float* __restrict__ CpB, const float* __restrict__ CnB,
                                               const float* __restrict__ bias,
                                               float* __restrict__ out) {
  const int r = threadIdx.x >> 5;            // row within block (0..7)
  const int lane = threadIdx.x & 31;
  const int row = blockIdx.x * QROWS + r;    // b*N + i
  const int b = row / N;
  const size_t bN = (size_t)b * N;
  const int d4 = lane * 4;
  const float f1v = f1[row];
  const float th = -f1v;
  const int g = bucket_of(th);
  const int base = bstart[b * (NB + 1) + g];
  const int end  = bstart[b * (NB + 1) + g + 1];
  float4 sn = *reinterpret_cast<const float4*>(&BNeg[((size_t)b * NB + g) * D + d4]);
  float4 sp = *reinterpret_cast<const float4*>(&BPos[((size_t)b * NB + g) * D + d4]);
  float cn = CnB[b * NB + g];
  float cp = CpB[b * NB + g];
  for (int e = base; e < end; ++e) {
    const float key = f2s[bN + e];
    const float wn_raw = wns[bN + e];
    const float wp_raw = wps[bN + e];
    const float4 v = *reinterpret_cast<const float4*>(&fts_s[(bN + e) * D + d4]);
    const bool neg = (key <= th);
    const float wn = neg ? wn_raw : 0.f;    // adding exact 0*v keeps bitwise identity
    const float wp = neg ? 0.f : wp_raw;
    sn.x += wn * v.x; sn.y += wn * v.y; sn.z += wn * v.z; sn.w += wn * v.w;
    sp.x += wp * v.x; sp.y += wp * v.y; sp.z += wp * v.z; sp.w += wp * v.w;
    cn += wn; cp += wp;
  }
  const float wqp = expf(f1v), wqn = expf(ALPHA * f1v);
  const float denom = wqp * cp + wqn * cn;
  const float inv = 1.0f / denom;
  const float4 bi = *reinterpret_cast<const float4*>(&bias[d4]);
  float4 val;
  val.x = (wqp * sp.x + wqn * sn.x) * inv + bi.x;
  val.y = (wqp * sp.y + wqn * sn.y) * inv + bi.y;
  val.z = (wqp * sp.z + wqn * sn.z) * inv + bi.z;
  val.w = (wqp * sp.w + wqn * sn.w) * inv + bi.w;
  val.x = val.x >= 0.f ? val.x : ALPHA * val.x;
  val.y = val.y >= 0.f ? val.y : ALPHA * val.y;
  val.z = val.z >= 0.f ? val.z : ALPHA * val.z;
  val.w = val.w >= 0.f ? val.w : ALPHA * val.w;
  *reinterpret_cast<float4*>(&out[(size_t)row * D + d4]) = val;
}

extern "C" void kernel_launch(void* const* d_in, const int* in_sizes, int n_in,
                              void* d_out, int out_size, void* d_ws, size_t ws_size,
                              hipStream_t stream) {
  const float* seq  = (const float*)d_in[0];
  const float* Wf   = (const float*)d_in[1];
  const float* w1   = (const float*)d_in[2];
  const float* b1   = (const float*)d_in[3];
  const float* w2   = (const float*)d_in[4];
  const float* b2   = (const float*)d_in[5];
  const float* bias = (const float*)d_in[6];
  float* out = (float*)d_out;

  char* ws = (char*)d_ws;
  size_t off = 0;
  auto alloc = [&](size_t bytes) -> void* {
    void* p = ws + off;
    off = (off + bytes + 255) & ~(size_t)255;
    return p;
  };

  float* fts    = (float*)alloc((size_t)M * D * 4);
  float* fts_s  = (float*)alloc((size_t)M * D * 4);
  float* f1     = (float*)alloc((size_t)M * 4);
  float* f2     = (float*)alloc((size_t)M * 4);
  float* f2s    = (float*)alloc((size_t)M * 4);
  int*   idxs   = (int*)  alloc((size_t)M * 4);
  float* wps    = (float*)alloc((size_t)M * 4);
  float* wns    = (float*)alloc((size_t)M * 4);
  int*   bid    = (int*)  alloc((size_t)M * 4);
  int*   histcnt= (int*)  alloc((size_t)B * P * NB * 4);
  int*   bstart = (int*)  alloc((size_t)B * (NB + 1) * 4);
  float* Wp     = (float*)alloc((size_t)B * NB * D * 4);
  float* Wn     = (float*)alloc((size_t)B * NB * D * 4);
  float* Cp     = (float*)alloc((size_t)B * NB * 4);
  float* Cn     = (float*)alloc((size_t)B * NB * 4);
  float* Gp     = (float*)alloc((size_t)B * NGRP * D * 4);
  float* Gn     = (float*)alloc((size_t)B * NGRP * D * 4);
  float* SGp    = (float*)alloc((size_t)B * NGRP * 4);
  float* SGn    = (float*)alloc((size_t)B * NGRP * 4);
  float* BPos   = (float*)alloc((size_t)B * NB * D * 4);
  float* BNeg   = (float*)alloc((size_t)B * NB * D * 4);
  float* CpB    = (float*)alloc((size_t)B * NB * 4);
  float* CnB    = (float*)alloc((size_t)B * NB * 4);

  hipLaunchKernelGGL(k_gemm,   dim3(M / 64),     dim3(512),  0, stream, seq, Wf, w1, b1, w2, b2, fts, f1, f2);
  hipLaunchKernelGGL(k_hist,   dim3(B * P),      dim3(256),  0, stream, f2, bid, histcnt);
  hipLaunchKernelGGL(k_bscan,  dim3(B),          dim3(1024), 0, stream, histcnt, bstart);
  hipLaunchKernelGGL(k_scatter,dim3(B * P),      dim3(256),  0, stream, f2, bid, histcnt, bstart, f2s, idxs, wps, wns);
  hipLaunchKernelGGL(k_perm,   dim3(M * D / 4 / 256), dim3(256), 0, stream, fts, idxs, fts_s);
  hipLaunchKernelGGL(k_bsum,   dim3(B * NBB),    dim3(128),  0, stream, fts_s, wps, wns, bstart, Wp, Wn, Cp, Cn);
  hipLaunchKernelGGL(k_gsumA,  dim3(B * NGRP),   dim3(128),  0, stream, Wp, Wn, Cp, Cn, Gp, Gn, SGp, SGn);
  hipLaunchKernelGGL(k_gscanB, dim3(B),          dim3(128),  0, stream, Gp, Gn, SGp, SGn);
  hipLaunchKernelGGL(k_gscanC, dim3(B * NGRP),   dim3(128),  0, stream, Wp, Wn, Cp, Cn, Gp, Gn, SGp, SGn,
                     BPos, BNeg, CpB, CnB);
  hipLaunchKernelGGL(k_query,  dim3(M / QROWS),  dim3(256),  0, stream, f1, f2s, wps, wns, fts_s, bstart,
                     BPos, BNeg, CpB, CnB, bias, out);
}

// Round 8
// 115.196 us; speedup vs baseline: 1.6463x; 1.0086x over previous
//
#include <hip/hip_runtime.h>
#include <cstddef>

#define ALPHA 0.2f
constexpr int B = 2, N = 8192, F = 256, D = 128;
constexpr int M = B * N;
constexpr int NB = 2048;          // value buckets per batch
constexpr int SUB = 256;          // elements per sub-block for stable scatter
constexpr int P = N / SUB;        // 32 sub-blocks per batch
constexpr int GB = 8;             // buckets per k_bsum block
constexpr int NBB = NB / GB;      // 256 bsum blocks per batch
constexpr int GSZ = 64;           // buckets per scan group
constexpr int NGRP = NB / GSZ;    // 32 groups per batch
constexpr int QROWS = 8;          // rows per k_query block
constexpr int DSL = 16;           // d's per k_scan slice
constexpr int NSL = D / DSL;      // 8 slices

// ---- fixed monotone bucket map (correct for ANY input via clamping) ----
#define BMIN (-10.0f)
#define BSCALE ((float)NB / 20.0f)
__device__ inline int bucket_of(float x) {
  int g = (int)((x - BMIN) * BSCALE);
  return g < 0 ? 0 : (g > NB - 1 ? NB - 1 : g);
}

// ---------------- GEMM + fused f1/f2 epilogue (transposed-A LDS) ----------------
__global__ __launch_bounds__(512) void k_gemm(const float* __restrict__ seq,
                                              const float* __restrict__ Wf,
                                              const float* __restrict__ w1,
                                              const float* __restrict__ b1,
                                              const float* __restrict__ w2,
                                              const float* __restrict__ b2,
                                              float* __restrict__ fts,
                                              float* __restrict__ f1,
                                              float* __restrict__ f2) {
  __shared__ float As[32][68];    // [k][row], padded: both MFMA-free operands read as b128
  __shared__ float Bs[32][128];
  const int m0 = blockIdx.x * 64;
  const int t = threadIdx.x;
  const int colg = t & 31;        // cols colg*4 .. +3
  const int rowg = t >> 5;        // rows rowg*4 .. +3 (16 groups)
  float acc[4][4];
#pragma unroll
  for (int r = 0; r < 4; ++r)
#pragma unroll
    for (int c = 0; c < 4; ++c) acc[r][c] = 0.f;

  for (int kc = 0; kc < F; kc += 32) {
    {  // A tile 64x32, stored transposed [k][row]
      int row = t >> 3, k4 = t & 7;
      const float4 v = *reinterpret_cast<const float4*>(
          &seq[(size_t)(m0 + row) * F + kc + k4 * 4]);
      As[k4 * 4 + 0][row] = v.x; As[k4 * 4 + 1][row] = v.y;
      As[k4 * 4 + 2][row] = v.z; As[k4 * 4 + 3][row] = v.w;
    }
#pragma unroll
    for (int it = 0; it < 2; ++it) {  // B tile 32x128
      int f = t + it * 512;
      int row = f >> 5, c4 = f & 31;
      *reinterpret_cast<float4*>(&Bs[row][c4 * 4]) =
          *reinterpret_cast<const float4*>(&Wf[(size_t)(kc + row) * D + c4 * 4]);
    }
    __syncthreads();
#pragma unroll
    for (int k = 0; k < 32; ++k) {
      const float4 a4 = *reinterpret_cast<const float4*>(&As[k][rowg * 4]);
      const float4 b4 = *reinterpret_cast<const float4*>(&Bs[k][colg * 4]);
      acc[0][0] += a4.x * b4.x; acc[0][1] += a4.x * b4.y; acc[0][2] += a4.x * b4.z; acc[0][3] += a4.x * b4.w;
      acc[1][0] += a4.y * b4.x; acc[1][1] += a4.y * b4.y; acc[1][2] += a4.y * b4.z; acc[1][3] += a4.y * b4.w;
      acc[2][0] += a4.z * b4.x; acc[2][1] += a4.z * b4.y; acc[2][2] += a4.z * b4.z; acc[2][3] += a4.z * b4.w;
      acc[3][0] += a4.w * b4.x; acc[3][1] += a4.w * b4.y; acc[3][2] += a4.w * b4.z; acc[3][3] += a4.w * b4.w;
    }
    __syncthreads();
  }
#pragma unroll
  for (int r = 0; r < 4; ++r) {
    float4 v = {acc[r][0], acc[r][1], acc[r][2], acc[r][3]};
    *reinterpret_cast<float4*>(&fts[(size_t)(m0 + rowg * 4 + r) * D + colg * 4]) = v;
  }
  const float w1v[4] = {w1[colg * 4], w1[colg * 4 + 1], w1[colg * 4 + 2], w1[colg * 4 + 3]};
  const float w2v[4] = {w2[colg * 4], w2[colg * 4 + 1], w2[colg * 4 + 2], w2[colg * 4 + 3]};
  const float b1v = b1[0], b2v = b2[0];
#pragma unroll
  for (int r = 0; r < 4; ++r) {
    float s1 = acc[r][0] * w1v[0] + acc[r][1] * w1v[1] + acc[r][2] * w1v[2] + acc[r][3] * w1v[3];
    float s2 = acc[r][0] * w2v[0] + acc[r][1] * w2v[1] + acc[r][2] * w2v[2] + acc[r][3] * w2v[3];
#pragma unroll
    for (int off = 16; off > 0; off >>= 1) {
      s1 += __shfl_down(s1, off, 32);
      s2 += __shfl_down(s2, off, 32);
    }
    if (colg == 0) {
      const int row = m0 + rowg * 4 + r;
      f1[row] = s1 + b1v;
      f2[row] = s2 + b2v;
    }
  }
}

// ---------------- per-sub-block histogram (deterministic) ----------------
__global__ __launch_bounds__(256) void k_hist(const float* __restrict__ f2,
                                              int* __restrict__ bid,
                                              int* __restrict__ histcnt) {
  __shared__ int hist[NB];
  const int b = blockIdx.x / P, p = blockIdx.x % P;
  const int t = threadIdx.x;
  for (int i = t; i < NB; i += 256) hist[i] = 0;
  const int j = p * SUB + t;
  float x = f2[b * N + j];
  int g = bucket_of(x);
  bid[b * N + j] = g;
  __syncthreads();
  atomicAdd(&hist[g], 1);
  __syncthreads();
  for (int i = t; i < NB; i += 256)
    histcnt[((size_t)(b * P + p)) * NB + i] = hist[i];
}

// ---------------- fused: per-block bucket scan + stable scatter + row permute ----------------
__global__ __launch_bounds__(256) void k_scat(const float* __restrict__ f2,
                                              const int* __restrict__ bid,
                                              const int* __restrict__ histcnt,
                                              int* __restrict__ bstart,
                                              const float* __restrict__ fts,
                                              float* __restrict__ fts_s,
                                              float* __restrict__ f2s,
                                              float* __restrict__ wps,
                                              float* __restrict__ wns) {
  __shared__ int bstart_lds[NB];
  __shared__ int bids[SUB];
  __shared__ int offs[SUB];
  __shared__ int wsum[4];
  const int b = blockIdx.x / P, p = blockIdx.x % P;
  const int t = threadIdx.x;
  const int lane = t & 63, wave = t >> 6;
  const size_t bN = (size_t)b * N;

  // phase A: bucket totals (8 buckets per thread) + exclusive scan in LDS
  int c[8];
  int locsum = 0;
#pragma unroll
  for (int i = 0; i < 8; ++i) {
    const int g = t * 8 + i;
    int s = 0;
    for (int pp = 0; pp < P; ++pp) s += histcnt[((size_t)(b * P + pp)) * NB + g];
    c[i] = s; locsum += s;
  }
  int incl = locsum;
#pragma unroll
  for (int off = 1; off < 64; off <<= 1) {
    int y = __shfl_up(incl, off);
    if (lane >= off) incl += y;
  }
  if (lane == 63) wsum[wave] = incl;
  __syncthreads();
  int woff = 0;
  for (int w = 0; w < wave; ++w) woff += wsum[w];
  incl += woff;
  int excl = incl - locsum;
#pragma unroll
  for (int i = 0; i < 8; ++i) { bstart_lds[t * 8 + i] = excl; excl += c[i]; }
  __syncthreads();
  if (p == 0) {  // publish for k_bsum / k_query
    for (int i = t; i < NB; i += 256) bstart[b * (NB + 1) + i] = bstart_lds[i];
    if (t == 0) bstart[b * (NB + 1) + NB] = N;
  }

  // phase B: stable deterministic scatter of this sub-block's 256 elements
  const int j = p * SUB + t;
  const int g = bid[bN + j];
  bids[t] = g;
  __syncthreads();
  int off = bstart_lds[g];
  for (int pp = 0; pp < p; ++pp) off += histcnt[((size_t)(b * P + pp)) * NB + g];
  for (int jj = 0; jj < t; ++jj) off += (bids[jj] == g);
  const float x = f2[bN + j];
  f2s[bN + off] = x;
  wps[bN + off] = expf(x);
  wns[bN + off] = expf(ALPHA * x);
  offs[t] = off;
  __syncthreads();

  // phase C: permute the 256 rows (fused k_perm), block-cooperative float4 copies
  for (int i = t; i < SUB * 32; i += 256) {
    const int r = i >> 5, q = i & 31;
    *reinterpret_cast<float4*>(&fts_s[(bN + offs[r]) * D + q * 4]) =
        *reinterpret_cast<const float4*>(&fts[(bN + p * SUB + r) * D + q * 4]);
  }
}

// ---------------- per-bucket weighted sums (streaming, unroll 4) ----------------
__global__ __launch_bounds__(128) void k_bsum(const float* __restrict__ fts_s,
                                              const float* __restrict__ wps,
                                              const float* __restrict__ wns,
                                              const int* __restrict__ bstart,
                                              float* __restrict__ Wp, float* __restrict__ Wn,
                                              float* __restrict__ Cp, float* __restrict__ Cn) {
  const int b = blockIdx.x / NBB, blk = blockIdx.x % NBB;
  const int d = threadIdx.x;
  const int gbase = blk * GB;
  const size_t bN = (size_t)b * N;
  for (int gg = 0; gg < GB; ++gg) {
    const int g = gbase + gg;
    const int e0 = bstart[b * (NB + 1) + g], e1 = bstart[b * (NB + 1) + g + 1];
    float ap = 0.f, an = 0.f, sp = 0.f, sn = 0.f;
    int e = e0;
    for (; e + 4 <= e1; e += 4) {
      const float* vp = &fts_s[(bN + e) * D + d];
      const float v0 = vp[0], v1 = vp[D], v2 = vp[2 * D], v3 = vp[3 * D];
      const float p0 = wps[bN + e], p1 = wps[bN + e + 1], p2 = wps[bN + e + 2], p3 = wps[bN + e + 3];
      const float n0 = wns[bN + e], n1 = wns[bN + e + 1], n2 = wns[bN + e + 2], n3 = wns[bN + e + 3];
      ap += p0 * v0 + p1 * v1 + p2 * v2 + p3 * v3;
      an += n0 * v0 + n1 * v1 + n2 * v2 + n3 * v3;
      sp += p0 + p1 + p2 + p3;
      sn += n0 + n1 + n2 + n3;
    }
    for (; e < e1; ++e) {
      const float v = fts_s[(bN + e) * D + d];
      const float wp = wps[bN + e], wn = wns[bN + e];
      ap += wp * v; an += wn * v; sp += wp; sn += wn;
    }
    Wp[((size_t)b * NB + g) * D + d] = ap;
    Wn[((size_t)b * NB + g) * D + d] = an;
    if (d == 0) { Cp[b * NB + g] = sp; Cn[b * NB + g] = sn; }
  }
}

// ---------------- fused 3-phase bucket-boundary scan (same association as before) ----------------
__global__ __launch_bounds__(512) void k_scan(const float* __restrict__ Wp, const float* __restrict__ Wn,
                                              const float* __restrict__ Cp, const float* __restrict__ Cn,
                                              float* __restrict__ BPos, float* __restrict__ BNeg,
                                              float* __restrict__ CpB, float* __restrict__ CnB) {
  __shared__ float gp[NGRP][DSL], gn[NGRP][DSL];
  __shared__ float cgp[NGRP], cgn[NGRP];
  const int b = blockIdx.x / NSL, sl = blockIdx.x % NSL;
  const int t = threadIdx.x;
  const int d16 = t & 15, grp = t >> 4;   // 32 groups x 16 d's = 512
  const int d = sl * DSL + d16;
  const size_t base = (size_t)b * NB;

  // phase 1: group sums (identical association to old k_gsumA)
  float sp = 0.f, sn = 0.f;
  for (int gg = 0; gg < GSZ; ++gg) {
    const int g = grp * GSZ + gg;
    sp += Wp[(base + g) * D + d];
    sn += Wn[(base + g) * D + d];
  }
  gp[grp][d16] = sp; gn[grp][d16] = sn;
  if (sl == 0 && d16 == 0) {
    float cp = 0.f, cn = 0.f;
    for (int gg = 0; gg < GSZ; ++gg) { const int g = grp * GSZ + gg; cp += Cp[base + g]; cn += Cn[base + g]; }
    cgp[grp] = cp; cgn[grp] = cn;
  }
  __syncthreads();

  // phase 2: exclusive scan of the 32 group sums (old k_gscanB)
  if (t < DSL) {
    float run = 0.f;
    for (int g2 = 0; g2 < NGRP; ++g2) { const float v = gn[g2][t]; gn[g2][t] = run; run += v; }
  } else if (t < 2 * DSL) {
    const int dd = t - DSL;
    float run = 0.f;
    for (int g2 = NGRP - 1; g2 >= 0; --g2) { const float v = gp[g2][dd]; gp[g2][dd] = run; run += v; }
  } else if (sl == 0 && t == 2 * DSL) {
    float run = 0.f;
    for (int g2 = 0; g2 < NGRP; ++g2) { const float v = cgn[g2]; cgn[g2] = run; run += v; }
  } else if (sl == 0 && t == 2 * DSL + 1) {
    float run = 0.f;
    for (int g2 = NGRP - 1; g2 >= 0; --g2) { const float v = cgp[g2]; cgp[g2] = run; run += v; }
  }
  __syncthreads();

  // phase 3: within-group running sums -> bucket-boundary values (old k_gscanC)
  float runn = gn[grp][d16];
  for (int gg = 0; gg < GSZ; ++gg) {
    const int g = grp * GSZ + gg;
    BNeg[(base + g) * D + d] = runn;
    runn += Wn[(base + g) * D + d];
  }
  float runp = gp[grp][d16];
  for (int gg = GSZ - 1; gg >= 0; --gg) {
    const int g = grp * GSZ + gg;
    BPos[(base + g) * D + d] = runp;
    runp += Wp[(base + g) * D + d];
  }
  if (sl == 0 && d16 == 0) {
    float rn = cgn[grp];
    for (int gg = 0; gg < GSZ; ++gg) { const int g = grp * GSZ + gg; CnB[base + g] = rn; rn += Cn[base + g]; }
    float rp = cgp[grp];
    for (int gg = GSZ - 1; gg >= 0; --gg) { const int g = grp * GSZ + gg; CpB[base + g] = rp; rp += Cp[base + g]; }
  }
}

// ---------------- query: 32 lanes x float4 per row, branchless boundary loop ----------------
__global__ __launch_bounds__(256) void k_query(const float* __restrict__ f1,
                                               const float* __restrict__ f2s,
                                               const float* __restrict__ wps,
                                               const float* __restrict__ wns,
                                               const float* __restrict__ fts_s,
                                               const int* __restrict__ bstart,
                                               const float* __restrict__ BPos, const float* __restrict__ BNeg,
                                               const float* __restrict__ CpB, const float* __restrict__ CnB,
                                               const float* __restrict__ bias,
                                               float* __restrict__ out) {
  const int r = threadIdx.x >> 5;            // row within block (0..7)
  const int lane = threadIdx.x & 31;
  const int row = blockIdx.x * QROWS + r;    // b*N + i
  const int b = row / N;
  const size_t bN = (size_t)b * N;
  const int d4 = lane * 4;
  const float f1v = f1[row];
  const float th = -f1v;
  const int g = bucket_of(th);
  const int base = bstart[b * (NB + 1) + g];
  const int end  = bstart[b * (NB + 1) + g + 1];
  float4 sn = *reinterpret_cast<const float4*>(&BNeg[((size_t)b * NB + g) * D + d4]);
  float4 sp = *reinterpret_cast<const float4*>(&BPos[((size_t)b * NB + g) * D + d4]);
  float cn = CnB[b * NB + g];
  float cp = CpB[b * NB + g];
  for (int e = base; e < end; ++e) {
    const float key = f2s[bN + e];
    const float wn_raw = wns[bN + e];
    const float wp_raw = wps[bN + e];
    const float4 v = *reinterpret_cast<const float4*>(&fts_s[(bN + e) * D + d4]);
    const bool neg = (key <= th);
    const float wn = neg ? wn_raw : 0.f;    // exact 0*v keeps bitwise identity
    const float wp = neg ? 0.f : wp_raw;
    sn.x += wn * v.x; sn.y += wn * v.y; sn.z += wn * v.z; sn.w += wn * v.w;
    sp.x += wp * v.x; sp.y += wp * v.y; sp.z += wp * v.z; sp.w += wp * v.w;
    cn += wn; cp += wp;
  }
  const float wqp = expf(f1v), wqn = expf(ALPHA * f1v);
  const float denom = wqp * cp + wqn * cn;
  const float inv = 1.0f / denom;
  const float4 bi = *reinterpret_cast<const float4*>(&bias[d4]);
  float4 val;
  val.x = (wqp * sp.x + wqn * sn.x) * inv + bi.x;
  val.y = (wqp * sp.y + wqn * sn.y) * inv + bi.y;
  val.z = (wqp * sp.z + wqn * sn.z) * inv + bi.z;
  val.w = (wqp * sp.w + wqn * sn.w) * inv + bi.w;
  val.x = val.x >= 0.f ? val.x : ALPHA * val.x;
  val.y = val.y >= 0.f ? val.y : ALPHA * val.y;
  val.z = val.z >= 0.f ? val.z : ALPHA * val.z;
  val.w = val.w >= 0.f ? val.w : ALPHA * val.w;
  *reinterpret_cast<float4*>(&out[(size_t)row * D + d4]) = val;
}

extern "C" void kernel_launch(void* const* d_in, const int* in_sizes, int n_in,
                              void* d_out, int out_size, void* d_ws, size_t ws_size,
                              hipStream_t stream) {
  const float* seq  = (const float*)d_in[0];
  const float* Wf   = (const float*)d_in[1];
  const float* w1   = (const float*)d_in[2];
  const float* b1   = (const float*)d_in[3];
  const float* w2   = (const float*)d_in[4];
  const float* b2   = (const float*)d_in[5];
  const float* bias = (const float*)d_in[6];
  float* out = (float*)d_out;

  char* ws = (char*)d_ws;
  size_t off = 0;
  auto alloc = [&](size_t bytes) -> void* {
    void* p = ws + off;
    off = (off + bytes + 255) & ~(size_t)255;
    return p;
  };

  float* fts    = (float*)alloc((size_t)M * D * 4);
  float* fts_s  = (float*)alloc((size_t)M * D * 4);
  float* f1     = (float*)alloc((size_t)M * 4);
  float* f2     = (float*)alloc((size_t)M * 4);
  float* f2s    = (float*)alloc((size_t)M * 4);
  float* wps    = (float*)alloc((size_t)M * 4);
  float* wns    = (float*)alloc((size_t)M * 4);
  int*   bid    = (int*)  alloc((size_t)M * 4);
  int*   histcnt= (int*)  alloc((size_t)B * P * NB * 4);
  int*   bstart = (int*)  alloc((size_t)B * (NB + 1) * 4);
  float* Wp     = (float*)alloc((size_t)B * NB * D * 4);
  float* Wn     = (float*)alloc((size_t)B * NB * D * 4);
  float* Cp     = (float*)alloc((size_t)B * NB * 4);
  float* Cn     = (float*)alloc((size_t)B * NB * 4);
  float* BPos   = (float*)alloc((size_t)B * NB * D * 4);
  float* BNeg   = (float*)alloc((size_t)B * NB * D * 4);
  float* CpB    = (float*)alloc((size_t)B * NB * 4);
  float* CnB    = (float*)alloc((size_t)B * NB * 4);

  hipLaunchKernelGGL(k_gemm,  dim3(M / 64),    dim3(512), 0, stream, seq, Wf, w1, b1, w2, b2, fts, f1, f2);
  hipLaunchKernelGGL(k_hist,  dim3(B * P),     dim3(256), 0, stream, f2, bid, histcnt);
  hipLaunchKernelGGL(k_scat,  dim3(B * P),     dim3(256), 0, stream, f2, bid, histcnt, bstart,
                     fts, fts_s, f2s, wps, wns);
  hipLaunchKernelGGL(k_bsum,  dim3(B * NBB),   dim3(128), 0, stream, fts_s, wps, wns, bstart, Wp, Wn, Cp, Cn);
  hipLaunchKernelGGL(k_scan,  dim3(B * NSL),   dim3(512), 0, stream, Wp, Wn, Cp, Cn, BPos, BNeg, CpB, CnB);
  hipLaunchKernelGGL(k_query, dim3(M / QROWS), dim3(256), 0, stream, f1, f2s, wps, wns, fts_s, bstart,
                     BPos, BNeg, CpB, CnB, bias, out);
}

// Round 9
// 96.701 us; speedup vs baseline: 1.9611x; 1.1913x over previous
//
#include <hip/hip_runtime.h>
#include <cstddef>

#define ALPHA 0.2f
constexpr int B = 2, N = 8192, F = 256, D = 128;
constexpr int M = B * N;
constexpr int NB = 2048;          // value buckets per batch
constexpr int SUB = 128;          // elements per sub-block for stable scatter
constexpr int P = N / SUB;        // 64 sub-blocks per batch
constexpr int GB = 2;             // buckets per k_bsum block
constexpr int NBB = NB / GB;      // 1024 bsum blocks per batch
constexpr int GSZ = 64;           // buckets per scan group
constexpr int NGRP = NB / GSZ;    // 32 groups per batch
constexpr int QROWS = 8;          // rows per k_query block
constexpr int DSL = 4;            // d's per k_scan slice
constexpr int NSL = D / DSL;      // 32 slices

// ---- fixed monotone bucket map (correct for ANY input via clamping) ----
#define BMIN (-10.0f)
#define BSCALE ((float)NB / 20.0f)
__device__ inline int bucket_of(float x) {
  int g = (int)((x - BMIN) * BSCALE);
  return g < 0 ? 0 : (g > NB - 1 ? NB - 1 : g);
}

// ---------------- GEMM + fused f1/f2 epilogue (transposed-A LDS) ----------------
__global__ __launch_bounds__(512) void k_gemm(const float* __restrict__ seq,
                                              const float* __restrict__ Wf,
                                              const float* __restrict__ w1,
                                              const float* __restrict__ b1,
                                              const float* __restrict__ w2,
                                              const float* __restrict__ b2,
                                              float* __restrict__ fts,
                                              float* __restrict__ f1,
                                              float* __restrict__ f2) {
  __shared__ float As[32][68];
  __shared__ float Bs[32][128];
  const int m0 = blockIdx.x * 64;
  const int t = threadIdx.x;
  const int colg = t & 31;
  const int rowg = t >> 5;
  float acc[4][4];
#pragma unroll
  for (int r = 0; r < 4; ++r)
#pragma unroll
    for (int c = 0; c < 4; ++c) acc[r][c] = 0.f;

  for (int kc = 0; kc < F; kc += 32) {
    {
      int row = t >> 3, k4 = t & 7;
      const float4 v = *reinterpret_cast<const float4*>(
          &seq[(size_t)(m0 + row) * F + kc + k4 * 4]);
      As[k4 * 4 + 0][row] = v.x; As[k4 * 4 + 1][row] = v.y;
      As[k4 * 4 + 2][row] = v.z; As[k4 * 4 + 3][row] = v.w;
    }
#pragma unroll
    for (int it = 0; it < 2; ++it) {
      int f = t + it * 512;
      int row = f >> 5, c4 = f & 31;
      *reinterpret_cast<float4*>(&Bs[row][c4 * 4]) =
          *reinterpret_cast<const float4*>(&Wf[(size_t)(kc + row) * D + c4 * 4]);
    }
    __syncthreads();
#pragma unroll
    for (int k = 0; k < 32; ++k) {
      const float4 a4 = *reinterpret_cast<const float4*>(&As[k][rowg * 4]);
      const float4 b4 = *reinterpret_cast<const float4*>(&Bs[k][colg * 4]);
      acc[0][0] += a4.x * b4.x; acc[0][1] += a4.x * b4.y; acc[0][2] += a4.x * b4.z; acc[0][3] += a4.x * b4.w;
      acc[1][0] += a4.y * b4.x; acc[1][1] += a4.y * b4.y; acc[1][2] += a4.y * b4.z; acc[1][3] += a4.y * b4.w;
      acc[2][0] += a4.z * b4.x; acc[2][1] += a4.z * b4.y; acc[2][2] += a4.z * b4.z; acc[2][3] += a4.z * b4.w;
      acc[3][0] += a4.w * b4.x; acc[3][1] += a4.w * b4.y; acc[3][2] += a4.w * b4.z; acc[3][3] += a4.w * b4.w;
    }
    __syncthreads();
  }
#pragma unroll
  for (int r = 0; r < 4; ++r) {
    float4 v = {acc[r][0], acc[r][1], acc[r][2], acc[r][3]};
    *reinterpret_cast<float4*>(&fts[(size_t)(m0 + rowg * 4 + r) * D + colg * 4]) = v;
  }
  const float w1v[4] = {w1[colg * 4], w1[colg * 4 + 1], w1[colg * 4 + 2], w1[colg * 4 + 3]};
  const float w2v[4] = {w2[colg * 4], w2[colg * 4 + 1], w2[colg * 4 + 2], w2[colg * 4 + 3]};
  const float b1v = b1[0], b2v = b2[0];
#pragma unroll
  for (int r = 0; r < 4; ++r) {
    float s1 = acc[r][0] * w1v[0] + acc[r][1] * w1v[1] + acc[r][2] * w1v[2] + acc[r][3] * w1v[3];
    float s2 = acc[r][0] * w2v[0] + acc[r][1] * w2v[1] + acc[r][2] * w2v[2] + acc[r][3] * w2v[3];
#pragma unroll
    for (int off = 16; off > 0; off >>= 1) {
      s1 += __shfl_down(s1, off, 32);
      s2 += __shfl_down(s2, off, 32);
    }
    if (colg == 0) {
      const int row = m0 + rowg * 4 + r;
      f1[row] = s1 + b1v;
      f2[row] = s2 + b2v;
    }
  }
}

// ---------------- per-sub-block histogram (deterministic) ----------------
__global__ __launch_bounds__(128) void k_hist(const float* __restrict__ f2,
                                              int* __restrict__ bid,
                                              int* __restrict__ histcnt) {
  __shared__ int hist[NB];
  const int b = blockIdx.x / P, p = blockIdx.x % P;
  const int t = threadIdx.x;
  for (int i = t; i < NB; i += 128) hist[i] = 0;
  const int j = p * SUB + t;
  float x = f2[b * N + j];
  int g = bucket_of(x);
  bid[b * N + j] = g;
  __syncthreads();
  atomicAdd(&hist[g], 1);
  __syncthreads();
  for (int i = t; i < NB; i += 128)
    histcnt[((size_t)(b * P + p)) * NB + i] = hist[i];
}

// ---------------- per-bucket prefix over sub-blocks + bucket totals ----------------
__global__ __launch_bounds__(256) void k_sub(const int* __restrict__ histcnt,
                                             int* __restrict__ substart,
                                             int* __restrict__ btot) {
  const int gid = blockIdx.x * 256 + threadIdx.x;  // 0 .. B*NB-1
  const int b = gid / NB, g = gid % NB;
  int run = 0;
  for (int pp = 0; pp < P; ++pp) {
    substart[((size_t)(b * P + pp)) * NB + g] = run;
    run += histcnt[((size_t)(b * P + pp)) * NB + g];
  }
  btot[b * NB + g] = run;
}

// ---------------- scatter of keys/weights (local bucket scan from btot) ----------------
__global__ __launch_bounds__(128) void k_scat(const float* __restrict__ f2,
                                              const int* __restrict__ bid,
                                              const int* __restrict__ substart,
                                              const int* __restrict__ btot,
                                              int* __restrict__ bstart,
                                              float* __restrict__ f2s,
                                              int* __restrict__ idxs,
                                              float* __restrict__ wps,
                                              float* __restrict__ wns) {
  __shared__ int bstart_lds[NB];
  __shared__ int bids[SUB];
  __shared__ int wsum2[2];
  const int b = blockIdx.x / P, p = blockIdx.x % P;
  const int t = threadIdx.x;
  const int lane = t & 63, wave = t >> 6;
  const size_t bN = (size_t)b * N;

  // local exclusive scan of btot (16 buckets per thread)
  int c[16];
  int loc = 0;
#pragma unroll
  for (int i = 0; i < 16; ++i) { c[i] = btot[b * NB + t * 16 + i]; loc += c[i]; }
  int incl = loc;
#pragma unroll
  for (int off = 1; off < 64; off <<= 1) {
    int y = __shfl_up(incl, off);
    if (lane >= off) incl += y;
  }
  if (lane == 63) wsum2[wave] = incl;
  __syncthreads();
  if (wave == 1) incl += wsum2[0];
  int excl = incl - loc;
#pragma unroll
  for (int i = 0; i < 16; ++i) { bstart_lds[t * 16 + i] = excl; excl += c[i]; }
  __syncthreads();
  if (p == 0) {
    for (int i = t; i < NB; i += 128) bstart[b * (NB + 1) + i] = bstart_lds[i];
    if (t == 0) bstart[b * (NB + 1) + NB] = N;
  }

  // stable deterministic scatter of this sub-block's elements
  const int j = p * SUB + t;
  const int g = bid[bN + j];
  bids[t] = g;
  __syncthreads();
  int off = bstart_lds[g] + substart[((size_t)(b * P + p)) * NB + g];
  for (int jj = 0; jj < t; ++jj) off += (bids[jj] == g);
  const float x = f2[bN + j];
  f2s[bN + off] = x;
  idxs[bN + off] = j;
  wps[bN + off] = expf(x);
  wns[bN + off] = expf(ALPHA * x);
}

// ---------------- permute fts into scattered order (full-grid gather) ----------------
__global__ __launch_bounds__(256) void k_perm(const float* __restrict__ fts,
                                              const int* __restrict__ idxs,
                                              float* __restrict__ fts_s) {
  const int tid = blockIdx.x * 256 + threadIdx.x;    // one float4 each
  const int eg = tid >> 5;                           // global scattered row (b*N+e)
  const int q = tid & 31;
  const int b = eg / N;
  const int j = idxs[eg];
  *reinterpret_cast<float4*>(&fts_s[(size_t)eg * D + q * 4]) =
      *reinterpret_cast<const float4*>(&fts[((size_t)b * N + j) * D + q * 4]);
}

// ---------------- per-bucket weighted sums (streaming, high TLP) ----------------
__global__ __launch_bounds__(128) void k_bsum(const float* __restrict__ fts_s,
                                              const float* __restrict__ wps,
                                              const float* __restrict__ wns,
                                              const int* __restrict__ bstart,
                                              float* __restrict__ Wp, float* __restrict__ Wn,
                                              float* __restrict__ Cp, float* __restrict__ Cn) {
  const int b = blockIdx.x / NBB, blk = blockIdx.x % NBB;
  const int d = threadIdx.x;
  const int gbase = blk * GB;
  const size_t bN = (size_t)b * N;
  for (int gg = 0; gg < GB; ++gg) {
    const int g = gbase + gg;
    const int e0 = bstart[b * (NB + 1) + g], e1 = bstart[b * (NB + 1) + g + 1];
    float ap = 0.f, an = 0.f, sp = 0.f, sn = 0.f;
    int e = e0;
    for (; e + 4 <= e1; e += 4) {
      const float* vp = &fts_s[(bN + e) * D + d];
      const float v0 = vp[0], v1 = vp[D], v2 = vp[2 * D], v3 = vp[3 * D];
      const float p0 = wps[bN + e], p1 = wps[bN + e + 1], p2 = wps[bN + e + 2], p3 = wps[bN + e + 3];
      const float n0 = wns[bN + e], n1 = wns[bN + e + 1], n2 = wns[bN + e + 2], n3 = wns[bN + e + 3];
      ap += p0 * v0 + p1 * v1 + p2 * v2 + p3 * v3;
      an += n0 * v0 + n1 * v1 + n2 * v2 + n3 * v3;
      sp += p0 + p1 + p2 + p3;
      sn += n0 + n1 + n2 + n3;
    }
    for (; e < e1; ++e) {
      const float v = fts_s[(bN + e) * D + d];
      const float wp = wps[bN + e], wn = wns[bN + e];
      ap += wp * v; an += wn * v; sp += wp; sn += wn;
    }
    Wp[((size_t)b * NB + g) * D + d] = ap;
    Wn[((size_t)b * NB + g) * D + d] = an;
    if (d == 0) { Cp[b * NB + g] = sp; Cn[b * NB + g] = sn; }
  }
}

// ---------------- fused 3-phase bucket-boundary scan (wide: 64 blocks) ----------------
__global__ __launch_bounds__(128) void k_scan(const float* __restrict__ Wp, const float* __restrict__ Wn,
                                              const float* __restrict__ Cp, const float* __restrict__ Cn,
                                              float* __restrict__ BPos, float* __restrict__ BNeg,
                                              float* __restrict__ CpB, float* __restrict__ CnB) {
  __shared__ float gp[NGRP][DSL], gn[NGRP][DSL];
  __shared__ float cgp[NGRP], cgn[NGRP];
  const int b = blockIdx.x / NSL, sl = blockIdx.x % NSL;
  const int t = threadIdx.x;                 // 128 = NGRP(32) x DSL(4)
  const int d4 = t & (DSL - 1), grp = t >> 2;
  const int d = sl * DSL + d4;
  const size_t base = (size_t)b * NB;

  // phase 1: group sums
  float sp = 0.f, sn = 0.f;
  for (int gg = 0; gg < GSZ; ++gg) {
    const int g = grp * GSZ + gg;
    sp += Wp[(base + g) * D + d];
    sn += Wn[(base + g) * D + d];
  }
  gp[grp][d4] = sp; gn[grp][d4] = sn;
  if (sl == 0 && d4 == 0) {
    float cp = 0.f, cn = 0.f;
    for (int gg = 0; gg < GSZ; ++gg) { const int g = grp * GSZ + gg; cp += Cp[base + g]; cn += Cn[base + g]; }
    cgp[grp] = cp; cgn[grp] = cn;
  }
  __syncthreads();

  // phase 2: exclusive scan of the 32 group sums
  if (t < DSL) {
    float run = 0.f;
    for (int g2 = 0; g2 < NGRP; ++g2) { const float v = gn[g2][t]; gn[g2][t] = run; run += v; }
  } else if (t < 2 * DSL) {
    const int dd = t - DSL;
    float run = 0.f;
    for (int g2 = NGRP - 1; g2 >= 0; --g2) { const float v = gp[g2][dd]; gp[g2][dd] = run; run += v; }
  } else if (sl == 0 && t == 2 * DSL) {
    float run = 0.f;
    for (int g2 = 0; g2 < NGRP; ++g2) { const float v = cgn[g2]; cgn[g2] = run; run += v; }
  } else if (sl == 0 && t == 2 * DSL + 1) {
    float run = 0.f;
    for (int g2 = NGRP - 1; g2 >= 0; --g2) { const float v = cgp[g2]; cgp[g2] = run; run += v; }
  }
  __syncthreads();

  // phase 3: within-group running sums -> bucket-boundary values
  float runn = gn[grp][d4];
  for (int gg = 0; gg < GSZ; ++gg) {
    const int g = grp * GSZ + gg;
    BNeg[(base + g) * D + d] = runn;
    runn += Wn[(base + g) * D + d];
  }
  float runp = gp[grp][d4];
  for (int gg = GSZ - 1; gg >= 0; --gg) {
    const int g = grp * GSZ + gg;
    BPos[(base + g) * D + d] = runp;
    runp += Wp[(base + g) * D + d];
  }
  if (sl == 0 && d4 == 0) {
    float rn = cgn[grp];
    for (int gg = 0; gg < GSZ; ++gg) { const int g = grp * GSZ + gg; CnB[base + g] = rn; rn += Cn[base + g]; }
    float rp = cgp[grp];
    for (int gg = GSZ - 1; gg >= 0; --gg) { const int g = grp * GSZ + gg; CpB[base + g] = rp; rp += Cp[base + g]; }
  }
}

// ---------------- query: 32 lanes x float4 per row, branchless boundary loop ----------------
__global__ __launch_bounds__(256) void k_query(const float* __restrict__ f1,
                                               const float* __restrict__ f2s,
                                               const float* __restrict__ wps,
                                               const float* __restrict__ wns,
                                               const float* __restrict__ fts_s,
                                               const int* __restrict__ bstart,
                                               const float* __restrict__ BPos, const float* __restrict__ BNeg,
                                               const float* __restrict__ CpB, const float* __restrict__ CnB,
                                               const float* __restrict__ bias,
                                               float* __restrict__ out) {
  const int r = threadIdx.x >> 5;
  const int lane = threadIdx.x & 31;
  const int row = blockIdx.x * QROWS + r;
  const int b = row / N;
  const size_t bN = (size_t)b * N;
  const int d4 = lane * 4;
  const float f1v = f1[row];
  const float th = -f1v;
  const int g = bucket_of(th);
  const int base = bstart[b * (NB + 1) + g];
  const int end  = bstart[b * (NB + 1) + g + 1];
  float4 sn = *reinterpret_cast<const float4*>(&BNeg[((size_t)b * NB + g) * D + d4]);
  float4 sp = *reinterpret_cast<const float4*>(&BPos[((size_t)b * NB + g) * D + d4]);
  float cn = CnB[b * NB + g];
  float cp = CpB[b * NB + g];
  for (int e = base; e < end; ++e) {
    const float key = f2s[bN + e];
    const float wn_raw = wns[bN + e];
    const float wp_raw = wps[bN + e];
    const float4 v = *reinterpret_cast<const float4*>(&fts_s[(bN + e) * D + d4]);
    const bool neg = (key <= th);
    const float wn = neg ? wn_raw : 0.f;
    const float wp = neg ? 0.f : wp_raw;
    sn.x += wn * v.x; sn.y += wn * v.y; sn.z += wn * v.z; sn.w += wn * v.w;
    sp.x += wp * v.x; sp.y += wp * v.y; sp.z += wp * v.z; sp.w += wp * v.w;
    cn += wn; cp += wp;
  }
  const float wqp = expf(f1v), wqn = expf(ALPHA * f1v);
  const float denom = wqp * cp + wqn * cn;
  const float inv = 1.0f / denom;
  const float4 bi = *reinterpret_cast<const float4*>(&bias[d4]);
  float4 val;
  val.x = (wqp * sp.x + wqn * sn.x) * inv + bi.x;
  val.y = (wqp * sp.y + wqn * sn.y) * inv + bi.y;
  val.z = (wqp * sp.z + wqn * sn.z) * inv + bi.z;
  val.w = (wqp * sp.w + wqn * sn.w) * inv + bi.w;
  val.x = val.x >= 0.f ? val.x : ALPHA * val.x;
  val.y = val.y >= 0.f ? val.y : ALPHA * val.y;
  val.z = val.z >= 0.f ? val.z : ALPHA * val.z;
  val.w = val.w >= 0.f ? val.w : ALPHA * val.w;
  *reinterpret_cast<float4*>(&out[(size_t)row * D + d4]) = val;
}

extern "C" void kernel_launch(void* const* d_in, const int* in_sizes, int n_in,
                              void* d_out, int out_size, void* d_ws, size_t ws_size,
                              hipStream_t stream) {
  const float* seq  = (const float*)d_in[0];
  const float* Wf   = (const float*)d_in[1];
  const float* w1   = (const float*)d_in[2];
  const float* b1   = (const float*)d_in[3];
  const float* w2   = (const float*)d_in[4];
  const float* b2   = (const float*)d_in[5];
  const float* bias = (const float*)d_in[6];
  float* out = (float*)d_out;

  char* ws = (char*)d_ws;
  size_t off = 0;
  auto alloc = [&](size_t bytes) -> void* {
    void* p = ws + off;
    off = (off + bytes + 255) & ~(size_t)255;
    return p;
  };

  float* fts     = (float*)alloc((size_t)M * D * 4);
  float* fts_s   = (float*)alloc((size_t)M * D * 4);
  float* f1      = (float*)alloc((size_t)M * 4);
  float* f2      = (float*)alloc((size_t)M * 4);
  float* f2s     = (float*)alloc((size_t)M * 4);
  int*   idxs    = (int*)  alloc((size_t)M * 4);
  float* wps     = (float*)alloc((size_t)M * 4);
  float* wns     = (float*)alloc((size_t)M * 4);
  int*   bid     = (int*)  alloc((size_t)M * 4);
  int*   histcnt = (int*)  alloc((size_t)B * P * NB * 4);
  int*   substart= (int*)  alloc((size_t)B * P * NB * 4);
  int*   btot    = (int*)  alloc((size_t)B * NB * 4);
  int*   bstart  = (int*)  alloc((size_t)B * (NB + 1) * 4);
  float* Wp      = (float*)alloc((size_t)B * NB * D * 4);
  float* Wn      = (float*)alloc((size_t)B * NB * D * 4);
  float* Cp      = (float*)alloc((size_t)B * NB * 4);
  float* Cn      = (float*)alloc((size_t)B * NB * 4);
  float* BPos    = (float*)alloc((size_t)B * NB * D * 4);
  float* BNeg    = (float*)alloc((size_t)B * NB * D * 4);
  float* CpB     = (float*)alloc((size_t)B * NB * 4);
  float* CnB     = (float*)alloc((size_t)B * NB * 4);

  hipLaunchKernelGGL(k_gemm,  dim3(M / 64),          dim3(512), 0, stream, seq, Wf, w1, b1, w2, b2, fts, f1, f2);
  hipLaunchKernelGGL(k_hist,  dim3(B * P),           dim3(128), 0, stream, f2, bid, histcnt);
  hipLaunchKernelGGL(k_sub,   dim3(B * NB / 256),    dim3(256), 0, stream, histcnt, substart, btot);
  hipLaunchKernelGGL(k_scat,  dim3(B * P),           dim3(128), 0, stream, f2, bid, substart, btot, bstart,
                     f2s, idxs, wps, wns);
  hipLaunchKernelGGL(k_perm,  dim3(M * D / 4 / 256), dim3(256), 0, stream, fts, idxs, fts_s);
  hipLaunchKernelGGL(k_bsum,  dim3(B * NBB),         dim3(128), 0, stream, fts_s, wps, wns, bstart, Wp, Wn, Cp, Cn);
  hipLaunchKernelGGL(k_scan,  dim3(B * NSL),         dim3(128), 0, stream, Wp, Wn, Cp, Cn, BPos, BNeg, CpB, CnB);
  hipLaunchKernelGGL(k_query, dim3(M / QROWS),       dim3(256), 0, stream, f1, f2s, wps, wns, fts_s, bstart,
                     BPos, BNeg, CpB, CnB, bias, out);
}